// Round 2
// baseline (408.228 us; speedup 1.0000x reference)
//
#include <hip/hip_runtime.h>

#define S 2048
#define D 1024
#define NH 16
#define HD 64
#define NBH 32          // B * NH
#define M 4096          // T * B
#define N3 3072         // 3 * D

typedef short s16x8 __attribute__((ext_vector_type(8)));
typedef float f32x4 __attribute__((ext_vector_type(4)));

__device__ __forceinline__ unsigned short f2bf(float f) {
  unsigned u = __builtin_bit_cast(unsigned, f);
  u += 0x7fffu + ((u >> 16) & 1u);
  return (unsigned short)(u >> 16);
}
__device__ __forceinline__ float bf2f(unsigned short h) {
  return __builtin_bit_cast(float, (unsigned)h << 16);
}

__device__ __forceinline__ float wsum(float v) {
  #pragma unroll
  for (int m = 1; m < 64; m <<= 1) v += __shfl_xor(v, m, 64);
  return v;
}

// ---------------------------------------------------------------------------
// Kernel 1: f32 GEMM  C[4096][3072] = A[4096][1024] @ W[3072][1024]^T + bias
// f32 on VALU: the sign of the correlation diagonal d[i] is discontinuous;
// bf16 GEMM noise would flip row validity vs the f32 reference.
// ---------------------------------------------------------------------------
__global__ __launch_bounds__(256) void gemm_qkv(const float* __restrict__ A,
                                                const float* __restrict__ W,
                                                const float* __restrict__ bias,
                                                float* __restrict__ C) {
  __shared__ float As[16][128];
  __shared__ float Bs[16][128];
  const int tid = threadIdx.x;
  const int tx = tid & 15, ty = tid >> 4;
  const int m0 = blockIdx.y * 128, n0 = blockIdx.x * 128;
  const int lrow = tid >> 1;            // 0..127
  const int lk8 = (tid & 1) << 3;       // 0 or 8
  const float* Ap = A + (size_t)(m0 + lrow) * D + lk8;
  const float* Wp = W + (size_t)(n0 + lrow) * D + lk8;

  float acc[8][8];
  #pragma unroll
  for (int i = 0; i < 8; ++i)
    #pragma unroll
    for (int j = 0; j < 8; ++j) acc[i][j] = 0.f;

  for (int k0 = 0; k0 < D; k0 += 16) {
    float4 av0 = *(const float4*)(Ap + k0);
    float4 av1 = *(const float4*)(Ap + k0 + 4);
    float4 wv0 = *(const float4*)(Wp + k0);
    float4 wv1 = *(const float4*)(Wp + k0 + 4);
    __syncthreads();
    As[lk8 + 0][lrow] = av0.x;  As[lk8 + 1][lrow] = av0.y;
    As[lk8 + 2][lrow] = av0.z;  As[lk8 + 3][lrow] = av0.w;
    As[lk8 + 4][lrow] = av1.x;  As[lk8 + 5][lrow] = av1.y;
    As[lk8 + 6][lrow] = av1.z;  As[lk8 + 7][lrow] = av1.w;
    Bs[lk8 + 0][lrow] = wv0.x;  Bs[lk8 + 1][lrow] = wv0.y;
    Bs[lk8 + 2][lrow] = wv0.z;  Bs[lk8 + 3][lrow] = wv0.w;
    Bs[lk8 + 4][lrow] = wv1.x;  Bs[lk8 + 5][lrow] = wv1.y;
    Bs[lk8 + 6][lrow] = wv1.z;  Bs[lk8 + 7][lrow] = wv1.w;
    __syncthreads();
    #pragma unroll
    for (int k = 0; k < 16; ++k) {
      float a[8], b[8];
      *(float4*)&a[0] = *(const float4*)&As[k][ty * 8];
      *(float4*)&a[4] = *(const float4*)&As[k][ty * 8 + 4];
      *(float4*)&b[0] = *(const float4*)&Bs[k][tx * 4];
      *(float4*)&b[4] = *(const float4*)&Bs[k][64 + tx * 4];
      #pragma unroll
      for (int i = 0; i < 8; ++i)
        #pragma unroll
        for (int j = 0; j < 8; ++j)
          acc[i][j] = fmaf(a[i], b[j], acc[i][j]);
    }
  }

  float bj[8];
  #pragma unroll
  for (int j = 0; j < 4; ++j) {
    bj[j]     = bias[n0 + tx * 4 + j];
    bj[j + 4] = bias[n0 + 64 + tx * 4 + j];
  }
  #pragma unroll
  for (int i = 0; i < 8; ++i) {
    const size_t row = (size_t)(m0 + ty * 8 + i);
    float4 o0, o1;
    o0.x = acc[i][0] + bj[0]; o0.y = acc[i][1] + bj[1];
    o0.z = acc[i][2] + bj[2]; o0.w = acc[i][3] + bj[3];
    o1.x = acc[i][4] + bj[4]; o1.y = acc[i][5] + bj[5];
    o1.z = acc[i][6] + bj[6]; o1.w = acc[i][7] + bj[7];
    *(float4*)&C[row * N3 + n0 + tx * 4]      = o0;
    *(float4*)&C[row * N3 + n0 + 64 + tx * 4] = o1;
  }
}

// ---------------------------------------------------------------------------
// Kernel 2: per-row stats + layout conversion.
// qc/kc centered rows -> SPLIT bf16 (hi + residual lo): hi+lo carries ~17
// mantissa bits so the QK^T numerator can be computed to ~f32 accuracy on
// bf16 MFMA (3-product split). rs = d>0 ? rsqrt(d) (NR-refined) : 0.
// rs=0 encodes the reference's NaN->0 row/col zeroing (c=0 -> exp=1).
// vt: V transposed -> bf16 [bh][64][S] (PV B-operand wants V^T row-major).
// ---------------------------------------------------------------------------
__global__ __launch_bounds__(256) void stats_k(const float* __restrict__ qkv,
                                               unsigned short* __restrict__ qhi,
                                               unsigned short* __restrict__ qlo,
                                               unsigned short* __restrict__ khi,
                                               unsigned short* __restrict__ klo,
                                               unsigned short* __restrict__ vt,
                                               float* __restrict__ rs) {
  __shared__ unsigned short VsT[64][65];
  const int tt = blockIdx.x, bh = blockIdx.y;
  const int b = bh >> 4, h = bh & 15;
  const int w = threadIdx.x >> 6, l = threadIdx.x & 63;

  for (int rr = 0; rr < 16; ++rr) {
    const int t = tt * 64 + w * 16 + rr;
    const size_t base = (size_t)(t * 2 + b) * N3 + h * HD;
    const float q = qkv[base + l];
    const float k = qkv[base + D + l];
    const float v = qkv[base + 2 * D + l];
    const float qm = wsum(q) * (1.f / 64.f);
    const float km = wsum(k) * (1.f / 64.f);
    const float qcv = q - qm, kcv = k - km;
    const float d = wsum(qcv * kcv);
    float rv = 0.f;
    if (d > 0.f) {
      rv = rsqrtf(d);
      rv = rv * (1.5f - 0.5f * d * rv * rv);   // one NR step -> ~0.5 ulp
    }
    const size_t ro = ((size_t)bh * S + t) * HD + l;
    const unsigned short qh = f2bf(qcv);
    const unsigned short kh = f2bf(kcv);
    qhi[ro] = qh;  qlo[ro] = f2bf(qcv - bf2f(qh));
    khi[ro] = kh;  klo[ro] = f2bf(kcv - bf2f(kh));
    if (l == 0) rs[(size_t)bh * S + t] = rv;
    VsT[l][w * 16 + rr] = f2bf(v);
  }
  __syncthreads();
  const int dd = threadIdx.x >> 2, seg = threadIdx.x & 3;
  unsigned pk[8];
  #pragma unroll
  for (int e = 0; e < 8; ++e) {
    unsigned l2 = VsT[dd][seg * 16 + 2 * e];
    unsigned h2 = VsT[dd][seg * 16 + 2 * e + 1];
    pk[e] = l2 | (h2 << 16);
  }
  unsigned short* dst = vt + ((size_t)bh * HD + dd) * S + tt * 64 + seg * 16;
  *(uint4*)dst       = make_uint4(pk[0], pk[1], pk[2], pk[3]);
  *(uint4*)(dst + 8) = make_uint4(pk[4], pk[5], pk[6], pk[7]);
}

// ---------------------------------------------------------------------------
// Kernel 3: fused correlation-softmax-PV, flash-style, bf16 MFMA 16x16x32.
// QK^T numerator via split-bf16 3-product MFMA (hi*hi + hi*lo + lo*hi):
// element rel error ~2^-18, so sign flips inside the clip(+-1)-saturated
// regime (the round-1 3.2e-3 failure mechanism) are suppressed ~300x.
// Logits clipped to [-1,1] -> exp without max tracking; single pass over KV.
// Block: 256 thr = 4 waves; QB=128 (32 q-rows/wave), KVB=64.
// ---------------------------------------------------------------------------
__global__ __launch_bounds__(256) void attn_k(const unsigned short* __restrict__ qhi,
                                              const unsigned short* __restrict__ qlo,
                                              const unsigned short* __restrict__ khi,
                                              const unsigned short* __restrict__ klo,
                                              const unsigned short* __restrict__ vt,
                                              const float* __restrict__ rs,
                                              float* __restrict__ out) {
  __shared__ unsigned short Kh[64][72];   // K-hi tile, padded stride 144B
  __shared__ unsigned short Kl[64][72];   // K-lo tile
  __shared__ unsigned short Vs[64][72];   // V^T tile
  __shared__ float Rs[64];
  __shared__ unsigned short Ps[128][72];  // P tile (wave-local rows)

  const int tid = threadIdx.x;
  const int w = tid >> 6, l = tid & 63;
  const int lo = l & 15, hi = l >> 4;
  const int qt = blockIdx.x, bh = blockIdx.y;

  const unsigned short* qhb = qhi + (size_t)bh * S * HD;
  const unsigned short* qlb = qlo + (size_t)bh * S * HD;
  const unsigned short* khb = khi + (size_t)bh * S * HD;
  const unsigned short* klb = klo + (size_t)bh * S * HD;
  const unsigned short* vbase = vt + (size_t)bh * HD * S;
  const float* rbase = rs + (size_t)bh * S;
  const int qrow0 = qt * 128 + w * 32;

  // Q fragments resident in registers: A-frag row=lo, k=hi*8.. (k-dim = hd)
  s16x8 aqh[2][2], aql[2][2];
  #pragma unroll
  for (int mi = 0; mi < 2; ++mi)
    #pragma unroll
    for (int ks = 0; ks < 2; ++ks) {
      const size_t off = (size_t)(qrow0 + mi * 16 + lo) * HD + ks * 32 + hi * 8;
      aqh[mi][ks] = *(const s16x8*)(qhb + off);
      aql[mi][ks] = *(const s16x8*)(qlb + off);
    }

  float rsq[2][4];
  #pragma unroll
  for (int mi = 0; mi < 2; ++mi)
    #pragma unroll
    for (int r = 0; r < 4; ++r)
      rsq[mi][r] = rbase[qrow0 + mi * 16 + hi * 4 + r];

  f32x4 oacc[2][4];
  float den[2][4];
  #pragma unroll
  for (int mi = 0; mi < 2; ++mi)
    #pragma unroll
    for (int nd = 0; nd < 4; ++nd) {
      oacc[mi][nd] = (f32x4){0.f, 0.f, 0.f, 0.f};
      den[mi][nd] = 0.f;
    }

  const int srow = tid >> 2;   // 0..63
  const int seg = tid & 3;     // 0..3

  for (int j0 = 0; j0 < S; j0 += 64) {
    const size_t koff = (size_t)(j0 + srow) * HD + seg * 16;
    uint4 kh0 = *(const uint4*)(khb + koff);
    uint4 kh1 = *(const uint4*)(khb + koff + 8);
    uint4 kl0 = *(const uint4*)(klb + koff);
    uint4 kl1 = *(const uint4*)(klb + koff + 8);
    uint4 vv0 = *(const uint4*)(vbase + (size_t)srow * S + j0 + seg * 16);
    uint4 vv1 = *(const uint4*)(vbase + (size_t)srow * S + j0 + seg * 16 + 8);
    float rv = (tid < 64) ? rbase[j0 + tid] : 0.f;
    __syncthreads();                       // prior iter's LDS reads done
    *(uint4*)&Kh[srow][seg * 16]     = kh0;
    *(uint4*)&Kh[srow][seg * 16 + 8] = kh1;
    *(uint4*)&Kl[srow][seg * 16]     = kl0;
    *(uint4*)&Kl[srow][seg * 16 + 8] = kl1;
    *(uint4*)&Vs[srow][seg * 16]     = vv0;
    *(uint4*)&Vs[srow][seg * 16 + 8] = vv1;
    if (tid < 64) Rs[tid] = rv;
    __syncthreads();

    // QK^T (split 3-product) + scale/clip/exp + pack P (wave-local rows)
    #pragma unroll
    for (int mi = 0; mi < 2; ++mi) {
      #pragma unroll
      for (int nj = 0; nj < 4; ++nj) {
        f32x4 acc = (f32x4){0.f, 0.f, 0.f, 0.f};
        #pragma unroll
        for (int ks = 0; ks < 2; ++ks) {
          s16x8 bkh = *(const s16x8*)&Kh[nj * 16 + lo][ks * 32 + hi * 8];
          s16x8 bkl = *(const s16x8*)&Kl[nj * 16 + lo][ks * 32 + hi * 8];
          acc = __builtin_amdgcn_mfma_f32_16x16x32_bf16(aqh[mi][ks], bkh, acc, 0, 0, 0);
          acc = __builtin_amdgcn_mfma_f32_16x16x32_bf16(aqh[mi][ks], bkl, acc, 0, 0, 0);
          acc = __builtin_amdgcn_mfma_f32_16x16x32_bf16(aql[mi][ks], bkh, acc, 0, 0, 0);
        }
        const float rj = Rs[nj * 16 + lo];
        #pragma unroll
        for (int r = 0; r < 4; ++r) {
          float c = acc[r] * rsq[mi][r] * rj;   // rs==0 -> c==0 -> exp==1
          c = fminf(1.f, fmaxf(-1.f, c));
          const float e = __expf(c);
          den[mi][r] += e;
          Ps[w * 32 + mi * 16 + hi * 4 + r][nj * 16 + lo] = f2bf(e);
        }
      }
    }

    // PV: A = P (rows of this wave), B = V^T tile
    #pragma unroll
    for (int mi = 0; mi < 2; ++mi) {
      s16x8 pa0 = *(const s16x8*)&Ps[w * 32 + mi * 16 + lo][hi * 8];
      s16x8 pa1 = *(const s16x8*)&Ps[w * 32 + mi * 16 + lo][32 + hi * 8];
      #pragma unroll
      for (int nd = 0; nd < 4; ++nd) {
        s16x8 bv0 = *(const s16x8*)&Vs[nd * 16 + lo][hi * 8];
        s16x8 bv1 = *(const s16x8*)&Vs[nd * 16 + lo][32 + hi * 8];
        oacc[mi][nd] = __builtin_amdgcn_mfma_f32_16x16x32_bf16(pa0, bv0, oacc[mi][nd], 0, 0, 0);
        oacc[mi][nd] = __builtin_amdgcn_mfma_f32_16x16x32_bf16(pa1, bv1, oacc[mi][nd], 0, 0, 0);
      }
    }
  }

  // reduce denominators across the 16 lanes sharing each row, then store
  #pragma unroll
  for (int mi = 0; mi < 2; ++mi)
    #pragma unroll
    for (int r = 0; r < 4; ++r) {
      float dsum = den[mi][r];
      dsum += __shfl_xor(dsum, 1, 64);
      dsum += __shfl_xor(dsum, 2, 64);
      dsum += __shfl_xor(dsum, 4, 64);
      dsum += __shfl_xor(dsum, 8, 64);
      den[mi][r] = 1.f / dsum;
    }
  #pragma unroll
  for (int mi = 0; mi < 2; ++mi)
    #pragma unroll
    for (int nd = 0; nd < 4; ++nd)
      #pragma unroll
      for (int r = 0; r < 4; ++r) {
        const size_t row = (size_t)bh * S + qrow0 + mi * 16 + hi * 4 + r;
        out[row * HD + nd * 16 + lo] = oacc[mi][nd][r] * den[mi][r];
      }
}

extern "C" void kernel_launch(void* const* d_in, const int* in_sizes, int n_in,
                              void* d_out, int out_size, void* d_ws, size_t ws_size,
                              hipStream_t stream) {
  const float* query = (const float*)d_in[0];
  const float* W     = (const float*)d_in[1];
  const float* bias  = (const float*)d_in[2];
  float* out = (float*)d_out;
  char* ws = (char*)d_ws;

  float*          qkv = (float*)ws;                          // 50,331,648 B
  unsigned short* qhi = (unsigned short*)(ws + 50331648);    //  8,388,608 B
  unsigned short* qlo = (unsigned short*)(ws + 58720256);    //  8,388,608 B
  unsigned short* khi = (unsigned short*)(ws + 67108864);    //  8,388,608 B
  unsigned short* klo = (unsigned short*)(ws + 75497472);    //  8,388,608 B
  unsigned short* vt  = (unsigned short*)(ws + 83886080);    //  8,388,608 B
  float*          rsb = (float*)(ws + 92274688);             //    262,144 B

  gemm_qkv<<<dim3(24, 32), 256, 0, stream>>>(query, W, bias, qkv);
  stats_k <<<dim3(32, 32), 256, 0, stream>>>(qkv, qhi, qlo, khi, klo, vt, rsb);
  attn_k  <<<dim3(16, 32), 256, 0, stream>>>(qhi, qlo, khi, klo, vt, rsb, out);
}

// Round 3
// 247.306 us; speedup vs baseline: 1.6507x; 1.6507x over previous
//
#include <hip/hip_runtime.h>

#define S 2048
#define D 1024
#define NH 16
#define HD 64
#define N3 3072         // 3 * D
#define M 4096          // T * B

typedef short s16x8 __attribute__((ext_vector_type(8)));
typedef float f32x4 __attribute__((ext_vector_type(4)));
typedef unsigned int u32;

__device__ __forceinline__ unsigned short f2bf(float f) {
  unsigned u = __builtin_bit_cast(unsigned, f);
  u += 0x7fffu + ((u >> 16) & 1u);
  return (unsigned short)(u >> 16);
}
__device__ __forceinline__ float bf2f(unsigned short h) {
  return __builtin_bit_cast(float, (unsigned)h << 16);
}

__device__ __forceinline__ float wsum(float v) {
  #pragma unroll
  for (int m = 1; m < 64; m <<= 1) v += __shfl_xor(v, m, 64);
  return v;
}

__device__ __forceinline__ void gload_lds16(const unsigned short* g, unsigned short* l) {
  __builtin_amdgcn_global_load_lds(
      (const __attribute__((address_space(1))) u32*)g,
      (__attribute__((address_space(3))) u32*)l, 16, 0, 0);
}

// ---------------------------------------------------------------------------
// Kernel 0: split f32 -> 3x bf16 (x = x1 + x2 + x3 + O(2^-27 x)).
// A (=query viewed [4096][1024], row m = t*2+b) and W [3072][1024].
// ---------------------------------------------------------------------------
__global__ __launch_bounds__(256) void split_k(const float* __restrict__ q,
                                               const float* __restrict__ w,
                                               unsigned short* __restrict__ A1,
                                               unsigned short* __restrict__ A2,
                                               unsigned short* __restrict__ A3,
                                               unsigned short* __restrict__ W1,
                                               unsigned short* __restrict__ W2,
                                               unsigned short* __restrict__ W3) {
  const size_t gid = (size_t)blockIdx.x * 256 + threadIdx.x;   // quad index
  const size_t NA = (size_t)M * D / 4;                          // 1048576
  float4 x;
  unsigned short* p1; unsigned short* p2; unsigned short* p3; size_t qi;
  if (gid < NA) {
    qi = gid;  x = ((const float4*)q)[qi];
    p1 = A1; p2 = A2; p3 = A3;
  } else {
    qi = gid - NA;  x = ((const float4*)w)[qi];
    p1 = W1; p2 = W2; p3 = W3;
  }
  ushort4 o1, o2, o3;
  float e[4] = {x.x, x.y, x.z, x.w};
  unsigned short h1[4], h2[4], h3[4];
  #pragma unroll
  for (int i = 0; i < 4; ++i) {
    h1[i] = f2bf(e[i]);          float r1 = e[i] - bf2f(h1[i]);
    h2[i] = f2bf(r1);            float r2 = r1 - bf2f(h2[i]);
    h3[i] = f2bf(r2);
  }
  o1 = make_ushort4(h1[0], h1[1], h1[2], h1[3]);
  o2 = make_ushort4(h2[0], h2[1], h2[2], h2[3]);
  o3 = make_ushort4(h3[0], h3[1], h3[2], h3[3]);
  *(ushort4*)&p1[qi * 4] = o1;
  *(ushort4*)&p2[qi * 4] = o2;
  *(ushort4*)&p3[qi * 4] = o3;
}

// ---------------------------------------------------------------------------
// Kernel 1: emulated-f32 GEMM on bf16 MFMA.
// C[4096][3072] = A @ W^T + bias, computed as sum over split-product
// segments: q,k cols (n<2048): A1W1+A2W1+A3W1+A1W2+A2W2+A1W3 (err ~2^-27);
// v cols (n>=2048): A1W1+A2W1 (bf16-level, sufficient downstream).
// m97 structure: 128x128 tile, BK=64, 4 waves (2x2), global_load_lds w=16,
// T2 XOR swizzle via pre-swizzled global source (rule #21: linear LDS dest).
// ---------------------------------------------------------------------------
__global__ __launch_bounds__(256) void gemm_mfma(const unsigned short* __restrict__ A1,
                                                 const unsigned short* __restrict__ A2,
                                                 const unsigned short* __restrict__ A3,
                                                 const unsigned short* __restrict__ W1,
                                                 const unsigned short* __restrict__ W2,
                                                 const unsigned short* __restrict__ W3,
                                                 const float* __restrict__ bias,
                                                 float* __restrict__ C) {
  __shared__ unsigned short As[128 * 64];
  __shared__ unsigned short Bs[128 * 64];
  const int tid = threadIdx.x;
  const int w = tid >> 6, l = tid & 63;
  const int lo = l & 15, hi = l >> 4;
  const int n0 = blockIdx.x * 128, m0 = blockIdx.y * 128;
  const int wr = w >> 1, wc = w & 1;          // wave tile 64x64

  const int nseg = (n0 >= 2048) ? 2 : 6;

  // staging map: call c stages rows c*32..c*32+31 (32 rows x 64 k = 4KB)
  const int srow = (tid >> 3) & 31;           // w*8 + (l>>3) in 0..31
  const int skc = tid & 7;                    // 16B unit within row

  f32x4 acc[4][4];
  #pragma unroll
  for (int mi = 0; mi < 4; ++mi)
    #pragma unroll
    for (int nj = 0; nj < 4; ++nj) acc[mi][nj] = (f32x4){0.f, 0.f, 0.f, 0.f};

  for (int s = 0; s < 6; ++s) {
    if (s >= nseg) break;
    const unsigned short* Ab;
    const unsigned short* Bb;
    switch (s) {                               // uniform scalar branch
      case 0: Ab = A1; Bb = W1; break;
      case 1: Ab = A2; Bb = W1; break;
      case 2: Ab = A3; Bb = W1; break;
      case 3: Ab = A1; Bb = W2; break;
      case 4: Ab = A2; Bb = W2; break;
      default: Ab = A1; Bb = W3; break;
    }
    Ab += (size_t)m0 * D;
    Bb += (size_t)n0 * D;

    for (int k0 = 0; k0 < D; k0 += 64) {
      __syncthreads();                         // prior iter's LDS reads done
      #pragma unroll
      for (int c = 0; c < 4; ++c) {
        const int row = c * 32 + srow;
        const int koct = skc ^ (row & 7);      // pre-swizzled source
        gload_lds16(Ab + (size_t)row * D + k0 + koct * 8,
                    As + c * 2048 + w * 512);
        gload_lds16(Bb + (size_t)row * D + k0 + koct * 8,
                    Bs + c * 2048 + w * 512);
      }
      __syncthreads();                         // vmcnt(0)+lgkmcnt(0) drain

      s16x8 af[4][2], bf[4][2];
      #pragma unroll
      for (int mi = 0; mi < 4; ++mi)
        #pragma unroll
        for (int ks = 0; ks < 2; ++ks) {
          const int row = wr * 64 + mi * 16 + lo;
          const int koct = (ks * 4 + hi) ^ (lo & 7);
          af[mi][ks] = *(const s16x8*)&As[row * 64 + koct * 8];
        }
      #pragma unroll
      for (int nj = 0; nj < 4; ++nj)
        #pragma unroll
        for (int ks = 0; ks < 2; ++ks) {
          const int row = wc * 64 + nj * 16 + lo;
          const int koct = (ks * 4 + hi) ^ (lo & 7);
          bf[nj][ks] = *(const s16x8*)&Bs[row * 64 + koct * 8];
        }
      #pragma unroll
      for (int mi = 0; mi < 4; ++mi)
        #pragma unroll
        for (int nj = 0; nj < 4; ++nj)
          #pragma unroll
          for (int ks = 0; ks < 2; ++ks)
            acc[mi][nj] = __builtin_amdgcn_mfma_f32_16x16x32_bf16(
                af[mi][ks], bf[nj][ks], acc[mi][nj], 0, 0, 0);
    }
  }

  float bj[4][4];
  #pragma unroll
  for (int nj = 0; nj < 4; ++nj) {
    const int n = n0 + wc * 64 + nj * 16 + lo;
    const float b = bias[n];
    #pragma unroll
    for (int r = 0; r < 4; ++r) bj[nj][r] = b;
  }
  #pragma unroll
  for (int mi = 0; mi < 4; ++mi)
    #pragma unroll
    for (int nj = 0; nj < 4; ++nj)
      #pragma unroll
      for (int r = 0; r < 4; ++r) {
        const int m = m0 + wr * 64 + mi * 16 + hi * 4 + r;
        const int n = n0 + wc * 64 + nj * 16 + lo;
        C[(size_t)m * N3 + n] = acc[mi][nj][r] + bj[nj][r];
      }
}

// ---------------------------------------------------------------------------
// Kernel 2: per-row stats + layout conversion (unchanged from round 2).
// ---------------------------------------------------------------------------
__global__ __launch_bounds__(256) void stats_k(const float* __restrict__ qkv,
                                               unsigned short* __restrict__ qhi,
                                               unsigned short* __restrict__ qlo,
                                               unsigned short* __restrict__ khi,
                                               unsigned short* __restrict__ klo,
                                               unsigned short* __restrict__ vt,
                                               float* __restrict__ rs) {
  __shared__ unsigned short VsT[64][65];
  const int tt = blockIdx.x, bh = blockIdx.y;
  const int b = bh >> 4, h = bh & 15;
  const int w = threadIdx.x >> 6, l = threadIdx.x & 63;

  for (int rr = 0; rr < 16; ++rr) {
    const int t = tt * 64 + w * 16 + rr;
    const size_t base = (size_t)(t * 2 + b) * N3 + h * HD;
    const float q = qkv[base + l];
    const float k = qkv[base + D + l];
    const float v = qkv[base + 2 * D + l];
    const float qm = wsum(q) * (1.f / 64.f);
    const float km = wsum(k) * (1.f / 64.f);
    const float qcv = q - qm, kcv = k - km;
    const float d = wsum(qcv * kcv);
    float rv = 0.f;
    if (d > 0.f) {
      rv = rsqrtf(d);
      rv = rv * (1.5f - 0.5f * d * rv * rv);   // one NR step
    }
    const size_t ro = ((size_t)bh * S + t) * HD + l;
    const unsigned short qh = f2bf(qcv);
    const unsigned short kh = f2bf(kcv);
    qhi[ro] = qh;  qlo[ro] = f2bf(qcv - bf2f(qh));
    khi[ro] = kh;  klo[ro] = f2bf(kcv - bf2f(kh));
    if (l == 0) rs[(size_t)bh * S + t] = rv;
    VsT[l][w * 16 + rr] = f2bf(v);
  }
  __syncthreads();
  const int dd = threadIdx.x >> 2, seg = threadIdx.x & 3;
  unsigned pk[8];
  #pragma unroll
  for (int e = 0; e < 8; ++e) {
    unsigned l2 = VsT[dd][seg * 16 + 2 * e];
    unsigned h2 = VsT[dd][seg * 16 + 2 * e + 1];
    pk[e] = l2 | (h2 << 16);
  }
  unsigned short* dst = vt + ((size_t)bh * HD + dd) * S + tt * 64 + seg * 16;
  *(uint4*)dst       = make_uint4(pk[0], pk[1], pk[2], pk[3]);
  *(uint4*)(dst + 8) = make_uint4(pk[4], pk[5], pk[6], pk[7]);
}

// ---------------------------------------------------------------------------
// Kernel 3: fused correlation-softmax-PV (unchanged from round 2).
// ---------------------------------------------------------------------------
__global__ __launch_bounds__(256) void attn_k(const unsigned short* __restrict__ qhi,
                                              const unsigned short* __restrict__ qlo,
                                              const unsigned short* __restrict__ khi,
                                              const unsigned short* __restrict__ klo,
                                              const unsigned short* __restrict__ vt,
                                              const float* __restrict__ rs,
                                              float* __restrict__ out) {
  __shared__ unsigned short Kh[64][72];
  __shared__ unsigned short Kl[64][72];
  __shared__ unsigned short Vs[64][72];
  __shared__ float Rs[64];
  __shared__ unsigned short Ps[128][72];

  const int tid = threadIdx.x;
  const int w = tid >> 6, l = tid & 63;
  const int lo = l & 15, hi = l >> 4;
  const int qt = blockIdx.x, bh = blockIdx.y;

  const unsigned short* qhb = qhi + (size_t)bh * S * HD;
  const unsigned short* qlb = qlo + (size_t)bh * S * HD;
  const unsigned short* khb = khi + (size_t)bh * S * HD;
  const unsigned short* klb = klo + (size_t)bh * S * HD;
  const unsigned short* vbase = vt + (size_t)bh * HD * S;
  const float* rbase = rs + (size_t)bh * S;
  const int qrow0 = qt * 128 + w * 32;

  s16x8 aqh[2][2], aql[2][2];
  #pragma unroll
  for (int mi = 0; mi < 2; ++mi)
    #pragma unroll
    for (int ks = 0; ks < 2; ++ks) {
      const size_t off = (size_t)(qrow0 + mi * 16 + lo) * HD + ks * 32 + hi * 8;
      aqh[mi][ks] = *(const s16x8*)(qhb + off);
      aql[mi][ks] = *(const s16x8*)(qlb + off);
    }

  float rsq[2][4];
  #pragma unroll
  for (int mi = 0; mi < 2; ++mi)
    #pragma unroll
    for (int r = 0; r < 4; ++r)
      rsq[mi][r] = rbase[qrow0 + mi * 16 + hi * 4 + r];

  f32x4 oacc[2][4];
  float den[2][4];
  #pragma unroll
  for (int mi = 0; mi < 2; ++mi)
    #pragma unroll
    for (int nd = 0; nd < 4; ++nd) {
      oacc[mi][nd] = (f32x4){0.f, 0.f, 0.f, 0.f};
      den[mi][nd] = 0.f;
    }

  const int srow = tid >> 2;
  const int seg = tid & 3;

  for (int j0 = 0; j0 < S; j0 += 64) {
    const size_t koff = (size_t)(j0 + srow) * HD + seg * 16;
    uint4 kh0 = *(const uint4*)(khb + koff);
    uint4 kh1 = *(const uint4*)(khb + koff + 8);
    uint4 kl0 = *(const uint4*)(klb + koff);
    uint4 kl1 = *(const uint4*)(klb + koff + 8);
    uint4 vv0 = *(const uint4*)(vbase + (size_t)srow * S + j0 + seg * 16);
    uint4 vv1 = *(const uint4*)(vbase + (size_t)srow * S + j0 + seg * 16 + 8);
    float rv = (tid < 64) ? rbase[j0 + tid] : 0.f;
    __syncthreads();
    *(uint4*)&Kh[srow][seg * 16]     = kh0;
    *(uint4*)&Kh[srow][seg * 16 + 8] = kh1;
    *(uint4*)&Kl[srow][seg * 16]     = kl0;
    *(uint4*)&Kl[srow][seg * 16 + 8] = kl1;
    *(uint4*)&Vs[srow][seg * 16]     = vv0;
    *(uint4*)&Vs[srow][seg * 16 + 8] = vv1;
    if (tid < 64) Rs[tid] = rv;
    __syncthreads();

    #pragma unroll
    for (int mi = 0; mi < 2; ++mi) {
      #pragma unroll
      for (int nj = 0; nj < 4; ++nj) {
        f32x4 acc = (f32x4){0.f, 0.f, 0.f, 0.f};
        #pragma unroll
        for (int ks = 0; ks < 2; ++ks) {
          s16x8 bkh = *(const s16x8*)&Kh[nj * 16 + lo][ks * 32 + hi * 8];
          s16x8 bkl = *(const s16x8*)&Kl[nj * 16 + lo][ks * 32 + hi * 8];
          acc = __builtin_amdgcn_mfma_f32_16x16x32_bf16(aqh[mi][ks], bkh, acc, 0, 0, 0);
          acc = __builtin_amdgcn_mfma_f32_16x16x32_bf16(aqh[mi][ks], bkl, acc, 0, 0, 0);
          acc = __builtin_amdgcn_mfma_f32_16x16x32_bf16(aql[mi][ks], bkh, acc, 0, 0, 0);
        }
        const float rj = Rs[nj * 16 + lo];
        #pragma unroll
        for (int r = 0; r < 4; ++r) {
          float c = acc[r] * rsq[mi][r] * rj;
          c = fminf(1.f, fmaxf(-1.f, c));
          const float e = __expf(c);
          den[mi][r] += e;
          Ps[w * 32 + mi * 16 + hi * 4 + r][nj * 16 + lo] = f2bf(e);
        }
      }
    }

    #pragma unroll
    for (int mi = 0; mi < 2; ++mi) {
      s16x8 pa0 = *(const s16x8*)&Ps[w * 32 + mi * 16 + lo][hi * 8];
      s16x8 pa1 = *(const s16x8*)&Ps[w * 32 + mi * 16 + lo][32 + hi * 8];
      #pragma unroll
      for (int nd = 0; nd < 4; ++nd) {
        s16x8 bv0 = *(const s16x8*)&Vs[nd * 16 + lo][hi * 8];
        s16x8 bv1 = *(const s16x8*)&Vs[nd * 16 + lo][32 + hi * 8];
        oacc[mi][nd] = __builtin_amdgcn_mfma_f32_16x16x32_bf16(pa0, bv0, oacc[mi][nd], 0, 0, 0);
        oacc[mi][nd] = __builtin_amdgcn_mfma_f32_16x16x32_bf16(pa1, bv1, oacc[mi][nd], 0, 0, 0);
      }
    }
  }

  #pragma unroll
  for (int mi = 0; mi < 2; ++mi)
    #pragma unroll
    for (int r = 0; r < 4; ++r) {
      float dsum = den[mi][r];
      dsum += __shfl_xor(dsum, 1, 64);
      dsum += __shfl_xor(dsum, 2, 64);
      dsum += __shfl_xor(dsum, 4, 64);
      dsum += __shfl_xor(dsum, 8, 64);
      den[mi][r] = 1.f / dsum;
    }
  #pragma unroll
  for (int mi = 0; mi < 2; ++mi)
    #pragma unroll
    for (int nd = 0; nd < 4; ++nd)
      #pragma unroll
      for (int r = 0; r < 4; ++r) {
        const size_t row = (size_t)bh * S + qrow0 + mi * 16 + hi * 4 + r;
        out[row * HD + nd * 16 + lo] = oacc[mi][nd][r] * den[mi][r];
      }
}

extern "C" void kernel_launch(void* const* d_in, const int* in_sizes, int n_in,
                              void* d_out, int out_size, void* d_ws, size_t ws_size,
                              hipStream_t stream) {
  const float* query = (const float*)d_in[0];
  const float* W     = (const float*)d_in[1];
  const float* bias  = (const float*)d_in[2];
  float* out = (float*)d_out;
  char* ws = (char*)d_ws;

  float*          qkv = (float*)ws;                          // [0, 50331648)
  // split parts live only between split_k and gemm_mfma:
  unsigned short* A1 = (unsigned short*)(ws + 50331648);     // 8388608
  unsigned short* A2 = (unsigned short*)(ws + 58720256);     // 8388608
  unsigned short* A3 = (unsigned short*)(ws + 67108864);     // 8388608
  unsigned short* W1 = (unsigned short*)(ws + 75497472);     // 6291456
  unsigned short* W2 = (unsigned short*)(ws + 81788928);     // 6291456
  unsigned short* W3 = (unsigned short*)(ws + 88080384);     // 6291456 -> end 94371840
  // stats outputs reuse the (dead) split region:
  unsigned short* qhi = (unsigned short*)(ws + 50331648);
  unsigned short* qlo = (unsigned short*)(ws + 58720256);
  unsigned short* khi = (unsigned short*)(ws + 67108864);
  unsigned short* klo = (unsigned short*)(ws + 75497472);
  unsigned short* vt  = (unsigned short*)(ws + 83886080);
  float*          rsb = (float*)(ws + 92274688);

  split_k  <<<dim3(7168), 256, 0, stream>>>(query, W, A1, A2, A3, W1, W2, W3);
  gemm_mfma<<<dim3(24, 32), 256, 0, stream>>>(A1, A2, A3, W1, W2, W3, bias, qkv);
  stats_k  <<<dim3(32, 32), 256, 0, stream>>>(qkv, qhi, qlo, khi, klo, vt, rsb);
  attn_k   <<<dim3(16, 32), 256, 0, stream>>>(qhi, qlo, khi, klo, vt, rsb, out);
}

// Round 4
// 192.847 us; speedup vs baseline: 2.1169x; 1.2824x over previous
//
#include <hip/hip_runtime.h>

#define S 2048
#define D 1024
#define NH 16
#define HD 64
#define N3 3072         // 3 * D
#define M 4096          // T * B

typedef short s16x8 __attribute__((ext_vector_type(8)));
typedef _Float16 f16x8 __attribute__((ext_vector_type(8)));
typedef float f32x4 __attribute__((ext_vector_type(4)));
typedef unsigned int u32;

__device__ __forceinline__ unsigned short f2bf(float f) {
  unsigned u = __builtin_bit_cast(unsigned, f);
  u += 0x7fffu + ((u >> 16) & 1u);
  return (unsigned short)(u >> 16);
}
__device__ __forceinline__ float bf2f(unsigned short h) {
  return __builtin_bit_cast(float, (unsigned)h << 16);
}

__device__ __forceinline__ float wsum(float v) {
  #pragma unroll
  for (int m = 1; m < 64; m <<= 1) v += __shfl_xor(v, m, 64);
  return v;
}

__device__ __forceinline__ void gload_lds16(const unsigned short* g, unsigned short* l) {
  __builtin_amdgcn_global_load_lds(
      (const __attribute__((address_space(1))) u32*)g,
      (__attribute__((address_space(3))) u32*)l, 16, 0, 0);
}

// ---------------------------------------------------------------------------
// Kernel 0: split f32 -> 2x fp16 limbs (11 mantissa bits each -> products to
// ~2^-22, truncation below f32's own rounding). Exact pow2 pre-scale (A x64,
// W x1024) keeps all significant residuals in fp16-normal range; epilogue
// multiplies by 2^-16 exactly.
// ---------------------------------------------------------------------------
__global__ __launch_bounds__(256) void split_k(const float* __restrict__ q,
                                               const float* __restrict__ w,
                                               unsigned short* __restrict__ A1,
                                               unsigned short* __restrict__ A2,
                                               unsigned short* __restrict__ W1,
                                               unsigned short* __restrict__ W2) {
  const size_t gid = (size_t)blockIdx.x * 256 + threadIdx.x;   // quad index
  const size_t NA = (size_t)M * D / 4;                          // 1048576
  float4 x;
  unsigned short* p1; unsigned short* p2; size_t qi; float scale;
  if (gid < NA) {
    qi = gid;  x = ((const float4*)q)[qi];
    p1 = A1; p2 = A2; scale = 64.f;
  } else {
    qi = gid - NA;  x = ((const float4*)w)[qi];
    p1 = W1; p2 = W2; scale = 1024.f;
  }
  float e[4] = {x.x * scale, x.y * scale, x.z * scale, x.w * scale};
  unsigned short h1[4], h2[4];
  #pragma unroll
  for (int i = 0; i < 4; ++i) {
    _Float16 a = (_Float16)e[i];
    float r = e[i] - (float)a;
    _Float16 b = (_Float16)r;
    h1[i] = __builtin_bit_cast(unsigned short, a);
    h2[i] = __builtin_bit_cast(unsigned short, b);
  }
  *(ushort4*)&p1[qi * 4] = make_ushort4(h1[0], h1[1], h1[2], h1[3]);
  *(ushort4*)&p2[qi * 4] = make_ushort4(h2[0], h2[1], h2[2], h2[3]);
}

// ---------------------------------------------------------------------------
// Kernel 1: emulated-f32 GEMM on fp16 MFMA.
// C[4096][3072] = (A' @ W'^T) * 2^-16 + bias.
// q,k cols (n<2048): A1W1 + A2W1 + A1W2 (err ~2^-22, below f32 rounding);
// v cols (n>=2048): A1W1 only (11-bit level, bf16 storage downstream anyway).
// Structure identical to the round-3 verified kernel (m97-style, 128x128,
// BK=64, global_load_lds w=16, XOR swizzle, 0 measured bank conflicts).
// ---------------------------------------------------------------------------
__global__ __launch_bounds__(256) void gemm_mfma(const unsigned short* __restrict__ A1,
                                                 const unsigned short* __restrict__ A2,
                                                 const unsigned short* __restrict__ W1,
                                                 const unsigned short* __restrict__ W2,
                                                 const float* __restrict__ bias,
                                                 float* __restrict__ C) {
  __shared__ unsigned short As[128 * 64];
  __shared__ unsigned short Bs[128 * 64];
  const int tid = threadIdx.x;
  const int w = tid >> 6, l = tid & 63;
  const int lo = l & 15, hi = l >> 4;
  const int n0 = blockIdx.x * 128, m0 = blockIdx.y * 128;
  const int wr = w >> 1, wc = w & 1;          // wave tile 64x64

  const int nseg = (n0 >= 2048) ? 1 : 3;

  const int srow = (tid >> 3) & 31;
  const int skc = tid & 7;

  f32x4 acc[4][4];
  #pragma unroll
  for (int mi = 0; mi < 4; ++mi)
    #pragma unroll
    for (int nj = 0; nj < 4; ++nj) acc[mi][nj] = (f32x4){0.f, 0.f, 0.f, 0.f};

  for (int s = 0; s < 3; ++s) {
    if (s >= nseg) break;
    const unsigned short* Ab;
    const unsigned short* Bb;
    switch (s) {                               // uniform scalar branch
      case 0: Ab = A1; Bb = W1; break;
      case 1: Ab = A2; Bb = W1; break;
      default: Ab = A1; Bb = W2; break;
    }
    Ab += (size_t)m0 * D;
    Bb += (size_t)n0 * D;

    for (int k0 = 0; k0 < D; k0 += 64) {
      __syncthreads();                         // prior iter's LDS reads done
      #pragma unroll
      for (int c = 0; c < 4; ++c) {
        const int row = c * 32 + srow;
        const int koct = skc ^ (row & 7);      // pre-swizzled source
        gload_lds16(Ab + (size_t)row * D + k0 + koct * 8,
                    As + c * 2048 + w * 512);
        gload_lds16(Bb + (size_t)row * D + k0 + koct * 8,
                    Bs + c * 2048 + w * 512);
      }
      __syncthreads();

      f16x8 af[4][2], bf[4][2];
      #pragma unroll
      for (int mi = 0; mi < 4; ++mi)
        #pragma unroll
        for (int ks = 0; ks < 2; ++ks) {
          const int row = wr * 64 + mi * 16 + lo;
          const int koct = (ks * 4 + hi) ^ (lo & 7);
          af[mi][ks] = *(const f16x8*)&As[row * 64 + koct * 8];
        }
      #pragma unroll
      for (int nj = 0; nj < 4; ++nj)
        #pragma unroll
        for (int ks = 0; ks < 2; ++ks) {
          const int row = wc * 64 + nj * 16 + lo;
          const int koct = (ks * 4 + hi) ^ (lo & 7);
          bf[nj][ks] = *(const f16x8*)&Bs[row * 64 + koct * 8];
        }
      #pragma unroll
      for (int mi = 0; mi < 4; ++mi)
        #pragma unroll
        for (int nj = 0; nj < 4; ++nj)
          #pragma unroll
          for (int ks = 0; ks < 2; ++ks)
            acc[mi][nj] = __builtin_amdgcn_mfma_f32_16x16x32_f16(
                af[mi][ks], bf[nj][ks], acc[mi][nj], 0, 0, 0);
    }
  }

  #pragma unroll
  for (int mi = 0; mi < 4; ++mi)
    #pragma unroll
    for (int nj = 0; nj < 4; ++nj) {
      const int n = n0 + wc * 64 + nj * 16 + lo;
      const float bj = bias[n];
      #pragma unroll
      for (int r = 0; r < 4; ++r) {
        const int m = m0 + wr * 64 + mi * 16 + hi * 4 + r;
        C[(size_t)m * N3 + n] = acc[mi][nj][r] * (1.f / 65536.f) + bj;
      }
    }
}

// ---------------------------------------------------------------------------
// Kernel 2: per-row stats + layout conversion (unchanged, verified r2/r3).
// ---------------------------------------------------------------------------
__global__ __launch_bounds__(256) void stats_k(const float* __restrict__ qkv,
                                               unsigned short* __restrict__ qhi,
                                               unsigned short* __restrict__ qlo,
                                               unsigned short* __restrict__ khi,
                                               unsigned short* __restrict__ klo,
                                               unsigned short* __restrict__ vt,
                                               float* __restrict__ rs) {
  __shared__ unsigned short VsT[64][65];
  const int tt = blockIdx.x, bh = blockIdx.y;
  const int b = bh >> 4, h = bh & 15;
  const int w = threadIdx.x >> 6, l = threadIdx.x & 63;

  for (int rr = 0; rr < 16; ++rr) {
    const int t = tt * 64 + w * 16 + rr;
    const size_t base = (size_t)(t * 2 + b) * N3 + h * HD;
    const float q = qkv[base + l];
    const float k = qkv[base + D + l];
    const float v = qkv[base + 2 * D + l];
    const float qm = wsum(q) * (1.f / 64.f);
    const float km = wsum(k) * (1.f / 64.f);
    const float qcv = q - qm, kcv = k - km;
    const float d = wsum(qcv * kcv);
    float rv = 0.f;
    if (d > 0.f) {
      rv = rsqrtf(d);
      rv = rv * (1.5f - 0.5f * d * rv * rv);   // one NR step
    }
    const size_t ro = ((size_t)bh * S + t) * HD + l;
    const unsigned short qh = f2bf(qcv);
    const unsigned short kh = f2bf(kcv);
    qhi[ro] = qh;  qlo[ro] = f2bf(qcv - bf2f(qh));
    khi[ro] = kh;  klo[ro] = f2bf(kcv - bf2f(kh));
    if (l == 0) rs[(size_t)bh * S + t] = rv;
    VsT[l][w * 16 + rr] = f2bf(v);
  }
  __syncthreads();
  const int dd = threadIdx.x >> 2, seg = threadIdx.x & 3;
  unsigned pk[8];
  #pragma unroll
  for (int e = 0; e < 8; ++e) {
    unsigned l2 = VsT[dd][seg * 16 + 2 * e];
    unsigned h2 = VsT[dd][seg * 16 + 2 * e + 1];
    pk[e] = l2 | (h2 << 16);
  }
  unsigned short* dst = vt + ((size_t)bh * HD + dd) * S + tt * 64 + seg * 16;
  *(uint4*)dst       = make_uint4(pk[0], pk[1], pk[2], pk[3]);
  *(uint4*)(dst + 8) = make_uint4(pk[4], pk[5], pk[6], pk[7]);
}

// ---------------------------------------------------------------------------
// Kernel 3: fused correlation-softmax-PV (unchanged, verified r2/r3).
// ---------------------------------------------------------------------------
__global__ __launch_bounds__(256) void attn_k(const unsigned short* __restrict__ qhi,
                                              const unsigned short* __restrict__ qlo,
                                              const unsigned short* __restrict__ khi,
                                              const unsigned short* __restrict__ klo,
                                              const unsigned short* __restrict__ vt,
                                              const float* __restrict__ rs,
                                              float* __restrict__ out) {
  __shared__ unsigned short Kh[64][72];
  __shared__ unsigned short Kl[64][72];
  __shared__ unsigned short Vs[64][72];
  __shared__ float Rs[64];
  __shared__ unsigned short Ps[128][72];

  const int tid = threadIdx.x;
  const int w = tid >> 6, l = tid & 63;
  const int lo = l & 15, hi = l >> 4;
  const int qt = blockIdx.x, bh = blockIdx.y;

  const unsigned short* qhb = qhi + (size_t)bh * S * HD;
  const unsigned short* qlb = qlo + (size_t)bh * S * HD;
  const unsigned short* khb = khi + (size_t)bh * S * HD;
  const unsigned short* klb = klo + (size_t)bh * S * HD;
  const unsigned short* vbase = vt + (size_t)bh * HD * S;
  const float* rbase = rs + (size_t)bh * S;
  const int qrow0 = qt * 128 + w * 32;

  s16x8 aqh[2][2], aql[2][2];
  #pragma unroll
  for (int mi = 0; mi < 2; ++mi)
    #pragma unroll
    for (int ks = 0; ks < 2; ++ks) {
      const size_t off = (size_t)(qrow0 + mi * 16 + lo) * HD + ks * 32 + hi * 8;
      aqh[mi][ks] = *(const s16x8*)(qhb + off);
      aql[mi][ks] = *(const s16x8*)(qlb + off);
    }

  float rsq[2][4];
  #pragma unroll
  for (int mi = 0; mi < 2; ++mi)
    #pragma unroll
    for (int r = 0; r < 4; ++r)
      rsq[mi][r] = rbase[qrow0 + mi * 16 + hi * 4 + r];

  f32x4 oacc[2][4];
  float den[2][4];
  #pragma unroll
  for (int mi = 0; mi < 2; ++mi)
    #pragma unroll
    for (int nd = 0; nd < 4; ++nd) {
      oacc[mi][nd] = (f32x4){0.f, 0.f, 0.f, 0.f};
      den[mi][nd] = 0.f;
    }

  const int srow = tid >> 2;
  const int seg = tid & 3;

  for (int j0 = 0; j0 < S; j0 += 64) {
    const size_t koff = (size_t)(j0 + srow) * HD + seg * 16;
    uint4 kh0 = *(const uint4*)(khb + koff);
    uint4 kh1 = *(const uint4*)(khb + koff + 8);
    uint4 kl0 = *(const uint4*)(klb + koff);
    uint4 kl1 = *(const uint4*)(klb + koff + 8);
    uint4 vv0 = *(const uint4*)(vbase + (size_t)srow * S + j0 + seg * 16);
    uint4 vv1 = *(const uint4*)(vbase + (size_t)srow * S + j0 + seg * 16 + 8);
    float rv = (tid < 64) ? rbase[j0 + tid] : 0.f;
    __syncthreads();
    *(uint4*)&Kh[srow][seg * 16]     = kh0;
    *(uint4*)&Kh[srow][seg * 16 + 8] = kh1;
    *(uint4*)&Kl[srow][seg * 16]     = kl0;
    *(uint4*)&Kl[srow][seg * 16 + 8] = kl1;
    *(uint4*)&Vs[srow][seg * 16]     = vv0;
    *(uint4*)&Vs[srow][seg * 16 + 8] = vv1;
    if (tid < 64) Rs[tid] = rv;
    __syncthreads();

    #pragma unroll
    for (int mi = 0; mi < 2; ++mi) {
      #pragma unroll
      for (int nj = 0; nj < 4; ++nj) {
        f32x4 acc = (f32x4){0.f, 0.f, 0.f, 0.f};
        #pragma unroll
        for (int ks = 0; ks < 2; ++ks) {
          s16x8 bkh = *(const s16x8*)&Kh[nj * 16 + lo][ks * 32 + hi * 8];
          s16x8 bkl = *(const s16x8*)&Kl[nj * 16 + lo][ks * 32 + hi * 8];
          acc = __builtin_amdgcn_mfma_f32_16x16x32_bf16(aqh[mi][ks], bkh, acc, 0, 0, 0);
          acc = __builtin_amdgcn_mfma_f32_16x16x32_bf16(aqh[mi][ks], bkl, acc, 0, 0, 0);
          acc = __builtin_amdgcn_mfma_f32_16x16x32_bf16(aql[mi][ks], bkh, acc, 0, 0, 0);
        }
        const float rj = Rs[nj * 16 + lo];
        #pragma unroll
        for (int r = 0; r < 4; ++r) {
          float c = acc[r] * rsq[mi][r] * rj;
          c = fminf(1.f, fmaxf(-1.f, c));
          const float e = __expf(c);
          den[mi][r] += e;
          Ps[w * 32 + mi * 16 + hi * 4 + r][nj * 16 + lo] = f2bf(e);
        }
      }
    }

    #pragma unroll
    for (int mi = 0; mi < 2; ++mi) {
      s16x8 pa0 = *(const s16x8*)&Ps[w * 32 + mi * 16 + lo][hi * 8];
      s16x8 pa1 = *(const s16x8*)&Ps[w * 32 + mi * 16 + lo][32 + hi * 8];
      #pragma unroll
      for (int nd = 0; nd < 4; ++nd) {
        s16x8 bv0 = *(const s16x8*)&Vs[nd * 16 + lo][hi * 8];
        s16x8 bv1 = *(const s16x8*)&Vs[nd * 16 + lo][32 + hi * 8];
        oacc[mi][nd] = __builtin_amdgcn_mfma_f32_16x16x32_bf16(pa0, bv0, oacc[mi][nd], 0, 0, 0);
        oacc[mi][nd] = __builtin_amdgcn_mfma_f32_16x16x32_bf16(pa1, bv1, oacc[mi][nd], 0, 0, 0);
      }
    }
  }

  #pragma unroll
  for (int mi = 0; mi < 2; ++mi)
    #pragma unroll
    for (int r = 0; r < 4; ++r) {
      float dsum = den[mi][r];
      dsum += __shfl_xor(dsum, 1, 64);
      dsum += __shfl_xor(dsum, 2, 64);
      dsum += __shfl_xor(dsum, 4, 64);
      dsum += __shfl_xor(dsum, 8, 64);
      den[mi][r] = 1.f / dsum;
    }
  #pragma unroll
  for (int mi = 0; mi < 2; ++mi)
    #pragma unroll
    for (int nd = 0; nd < 4; ++nd)
      #pragma unroll
      for (int r = 0; r < 4; ++r) {
        const size_t row = (size_t)bh * S + qrow0 + mi * 16 + hi * 4 + r;
        out[row * HD + nd * 16 + lo] = oacc[mi][nd][r] * den[mi][r];
      }
}

extern "C" void kernel_launch(void* const* d_in, const int* in_sizes, int n_in,
                              void* d_out, int out_size, void* d_ws, size_t ws_size,
                              hipStream_t stream) {
  const float* query = (const float*)d_in[0];
  const float* W     = (const float*)d_in[1];
  const float* bias  = (const float*)d_in[2];
  float* out = (float*)d_out;
  char* ws = (char*)d_ws;

  float*          qkv = (float*)ws;                          // [0, 50331648)
  // fp16 split planes live only between split_k and gemm_mfma:
  unsigned short* A1 = (unsigned short*)(ws + 50331648);     // 8388608
  unsigned short* A2 = (unsigned short*)(ws + 58720256);     // 8388608
  unsigned short* W1 = (unsigned short*)(ws + 67108864);     // 6291456
  unsigned short* W2 = (unsigned short*)(ws + 73400320);     // 6291456 -> 79691776
  // stats outputs reuse the (dead) split region:
  unsigned short* qhi = (unsigned short*)(ws + 50331648);
  unsigned short* qlo = (unsigned short*)(ws + 58720256);
  unsigned short* khi = (unsigned short*)(ws + 67108864);
  unsigned short* klo = (unsigned short*)(ws + 75497472);
  unsigned short* vt  = (unsigned short*)(ws + 83886080);
  float*          rsb = (float*)(ws + 92274688);

  split_k  <<<dim3(7168), 256, 0, stream>>>(query, W, A1, A2, W1, W2);
  gemm_mfma<<<dim3(24, 32), 256, 0, stream>>>(A1, A2, W1, W2, bias, qkv);
  stats_k  <<<dim3(32, 32), 256, 0, stream>>>(qkv, qhi, qlo, khi, klo, vt, rsb);
  attn_k   <<<dim3(16, 32), 256, 0, stream>>>(qhi, qlo, khi, klo, vt, rsb, out);
}

// Round 5
// 192.427 us; speedup vs baseline: 2.1215x; 1.0022x over previous
//
#include <hip/hip_runtime.h>

#define S 2048
#define D 1024
#define NH 16
#define HD 64
#define N3 3072         // 3 * D
#define M 4096          // T * B

typedef short s16x8 __attribute__((ext_vector_type(8)));
typedef _Float16 f16x8 __attribute__((ext_vector_type(8)));
typedef float f32x4 __attribute__((ext_vector_type(4)));
typedef unsigned int u32;

__device__ __forceinline__ unsigned short f2bf(float f) {
  unsigned u = __builtin_bit_cast(unsigned, f);
  u += 0x7fffu + ((u >> 16) & 1u);
  return (unsigned short)(u >> 16);
}
__device__ __forceinline__ float bf2f(unsigned short h) {
  return __builtin_bit_cast(float, (unsigned)h << 16);
}

__device__ __forceinline__ float wsum(float v) {
  #pragma unroll
  for (int m = 1; m < 64; m <<= 1) v += __shfl_xor(v, m, 64);
  return v;
}

__device__ __forceinline__ void gload_lds16(const unsigned short* g, unsigned short* l) {
  __builtin_amdgcn_global_load_lds(
      (const __attribute__((address_space(1))) u32*)g,
      (__attribute__((address_space(3))) u32*)l, 16, 0, 0);
}

// ---------------------------------------------------------------------------
// Kernel 0: split f32 -> 2x fp16 limbs (verified r4).
// ---------------------------------------------------------------------------
__global__ __launch_bounds__(256) void split_k(const float* __restrict__ q,
                                               const float* __restrict__ w,
                                               unsigned short* __restrict__ A1,
                                               unsigned short* __restrict__ A2,
                                               unsigned short* __restrict__ W1,
                                               unsigned short* __restrict__ W2) {
  const size_t gid = (size_t)blockIdx.x * 256 + threadIdx.x;   // quad index
  const size_t NA = (size_t)M * D / 4;                          // 1048576
  float4 x;
  unsigned short* p1; unsigned short* p2; size_t qi; float scale;
  if (gid < NA) {
    qi = gid;  x = ((const float4*)q)[qi];
    p1 = A1; p2 = A2; scale = 64.f;
  } else {
    qi = gid - NA;  x = ((const float4*)w)[qi];
    p1 = W1; p2 = W2; scale = 1024.f;
  }
  float e[4] = {x.x * scale, x.y * scale, x.z * scale, x.w * scale};
  unsigned short h1[4], h2[4];
  #pragma unroll
  for (int i = 0; i < 4; ++i) {
    _Float16 a = (_Float16)e[i];
    float r = e[i] - (float)a;
    _Float16 b = (_Float16)r;
    h1[i] = __builtin_bit_cast(unsigned short, a);
    h2[i] = __builtin_bit_cast(unsigned short, b);
  }
  *(ushort4*)&p1[qi * 4] = make_ushort4(h1[0], h1[1], h1[2], h1[3]);
  *(ushort4*)&p2[qi * 4] = make_ushort4(h2[0], h2[1], h2[2], h2[3]);
}

// ---------------------------------------------------------------------------
// Kernel 1: emulated-f32 GEMM on fp16 MFMA (verified r4, unchanged).
// ---------------------------------------------------------------------------
__global__ __launch_bounds__(256) void gemm_mfma(const unsigned short* __restrict__ A1,
                                                 const unsigned short* __restrict__ A2,
                                                 const unsigned short* __restrict__ W1,
                                                 const unsigned short* __restrict__ W2,
                                                 const float* __restrict__ bias,
                                                 float* __restrict__ C) {
  __shared__ unsigned short As[128 * 64];
  __shared__ unsigned short Bs[128 * 64];
  const int tid = threadIdx.x;
  const int w = tid >> 6, l = tid & 63;
  const int lo = l & 15, hi = l >> 4;
  const int n0 = blockIdx.x * 128, m0 = blockIdx.y * 128;
  const int wr = w >> 1, wc = w & 1;          // wave tile 64x64

  const int nseg = (n0 >= 2048) ? 1 : 3;

  const int srow = (tid >> 3) & 31;
  const int skc = tid & 7;

  f32x4 acc[4][4];
  #pragma unroll
  for (int mi = 0; mi < 4; ++mi)
    #pragma unroll
    for (int nj = 0; nj < 4; ++nj) acc[mi][nj] = (f32x4){0.f, 0.f, 0.f, 0.f};

  for (int s = 0; s < 3; ++s) {
    if (s >= nseg) break;
    const unsigned short* Ab;
    const unsigned short* Bb;
    switch (s) {                               // uniform scalar branch
      case 0: Ab = A1; Bb = W1; break;
      case 1: Ab = A2; Bb = W1; break;
      default: Ab = A1; Bb = W2; break;
    }
    Ab += (size_t)m0 * D;
    Bb += (size_t)n0 * D;

    for (int k0 = 0; k0 < D; k0 += 64) {
      __syncthreads();                         // prior iter's LDS reads done
      #pragma unroll
      for (int c = 0; c < 4; ++c) {
        const int row = c * 32 + srow;
        const int koct = skc ^ (row & 7);      // pre-swizzled source
        gload_lds16(Ab + (size_t)row * D + k0 + koct * 8,
                    As + c * 2048 + w * 512);
        gload_lds16(Bb + (size_t)row * D + k0 + koct * 8,
                    Bs + c * 2048 + w * 512);
      }
      __syncthreads();

      f16x8 af[4][2], bf[4][2];
      #pragma unroll
      for (int mi = 0; mi < 4; ++mi)
        #pragma unroll
        for (int ks = 0; ks < 2; ++ks) {
          const int row = wr * 64 + mi * 16 + lo;
          const int koct = (ks * 4 + hi) ^ (lo & 7);
          af[mi][ks] = *(const f16x8*)&As[row * 64 + koct * 8];
        }
      #pragma unroll
      for (int nj = 0; nj < 4; ++nj)
        #pragma unroll
        for (int ks = 0; ks < 2; ++ks) {
          const int row = wc * 64 + nj * 16 + lo;
          const int koct = (ks * 4 + hi) ^ (lo & 7);
          bf[nj][ks] = *(const f16x8*)&Bs[row * 64 + koct * 8];
        }
      #pragma unroll
      for (int mi = 0; mi < 4; ++mi)
        #pragma unroll
        for (int nj = 0; nj < 4; ++nj)
          #pragma unroll
          for (int ks = 0; ks < 2; ++ks)
            acc[mi][nj] = __builtin_amdgcn_mfma_f32_16x16x32_f16(
                af[mi][ks], bf[nj][ks], acc[mi][nj], 0, 0, 0);
    }
  }

  #pragma unroll
  for (int mi = 0; mi < 4; ++mi)
    #pragma unroll
    for (int nj = 0; nj < 4; ++nj) {
      const int n = n0 + wc * 64 + nj * 16 + lo;
      const float bj = bias[n];
      #pragma unroll
      for (int r = 0; r < 4; ++r) {
        const int m = m0 + wr * 64 + mi * 16 + hi * 4 + r;
        C[(size_t)m * N3 + n] = acc[mi][nj][r] * (1.f / 65536.f) + bj;
      }
    }
}

// ---------------------------------------------------------------------------
// Kernel 2: per-row stats + layout conversion (unchanged, verified r2-r4).
// ---------------------------------------------------------------------------
__global__ __launch_bounds__(256) void stats_k(const float* __restrict__ qkv,
                                               unsigned short* __restrict__ qhi,
                                               unsigned short* __restrict__ qlo,
                                               unsigned short* __restrict__ khi,
                                               unsigned short* __restrict__ klo,
                                               unsigned short* __restrict__ vt,
                                               float* __restrict__ rs) {
  __shared__ unsigned short VsT[64][65];
  const int tt = blockIdx.x, bh = blockIdx.y;
  const int b = bh >> 4, h = bh & 15;
  const int w = threadIdx.x >> 6, l = threadIdx.x & 63;

  for (int rr = 0; rr < 16; ++rr) {
    const int t = tt * 64 + w * 16 + rr;
    const size_t base = (size_t)(t * 2 + b) * N3 + h * HD;
    const float q = qkv[base + l];
    const float k = qkv[base + D + l];
    const float v = qkv[base + 2 * D + l];
    const float qm = wsum(q) * (1.f / 64.f);
    const float km = wsum(k) * (1.f / 64.f);
    const float qcv = q - qm, kcv = k - km;
    const float d = wsum(qcv * kcv);
    float rv = 0.f;
    if (d > 0.f) {
      rv = rsqrtf(d);
      rv = rv * (1.5f - 0.5f * d * rv * rv);   // one NR step
    }
    const size_t ro = ((size_t)bh * S + t) * HD + l;
    const unsigned short qh = f2bf(qcv);
    const unsigned short kh = f2bf(kcv);
    qhi[ro] = qh;  qlo[ro] = f2bf(qcv - bf2f(qh));
    khi[ro] = kh;  klo[ro] = f2bf(kcv - bf2f(kh));
    if (l == 0) rs[(size_t)bh * S + t] = rv;
    VsT[l][w * 16 + rr] = f2bf(v);
  }
  __syncthreads();
  const int dd = threadIdx.x >> 2, seg = threadIdx.x & 3;
  unsigned pk[8];
  #pragma unroll
  for (int e = 0; e < 8; ++e) {
    unsigned l2 = VsT[dd][seg * 16 + 2 * e];
    unsigned h2 = VsT[dd][seg * 16 + 2 * e + 1];
    pk[e] = l2 | (h2 << 16);
  }
  unsigned short* dst = vt + ((size_t)bh * HD + dd) * S + tt * 64 + seg * 16;
  *(uint4*)dst       = make_uint4(pk[0], pk[1], pk[2], pk[3]);
  *(uint4*)(dst + 8) = make_uint4(pk[4], pk[5], pk[6], pk[7]);
}

// ---------------------------------------------------------------------------
// Kernel 3: fused correlation-softmax-PV.
// r5 changes: (a) all LDS tiles -> linear 64-wide + XOR-granule layout
// (the gemm-verified zero-conflict pattern); (b) K/V staging via
// global_load_lds w=16 with pre-swizzled source (linear dest, rule #21);
// (c) Rs LDS dropped (per-lane global reads) -> LDS = 40960B = 4 blocks/CU;
// (d) T1 bijective XCD swizzle: 4 bh's K/V (3MB) pinned per XCD L2.
// ---------------------------------------------------------------------------
__global__ __launch_bounds__(256) void attn_k(const unsigned short* __restrict__ qhi,
                                              const unsigned short* __restrict__ qlo,
                                              const unsigned short* __restrict__ khi,
                                              const unsigned short* __restrict__ klo,
                                              const unsigned short* __restrict__ vt,
                                              const float* __restrict__ rs,
                                              float* __restrict__ out) {
  __shared__ unsigned short Kh[64 * 64];   // [row j][64 k], XOR-granule
  __shared__ unsigned short Kl[64 * 64];
  __shared__ unsigned short Vsm[64 * 64];  // [row d][64 j], XOR-granule
  __shared__ unsigned short Ps[128 * 64];  // [row q][64 j], XOR-granule

  const int tid = threadIdx.x;
  const int w = tid >> 6, l = tid & 63;
  const int lo = l & 15, hi = l >> 4;

  // T1: XCD-aware swizzle (512 = 8 XCD x 64, exact -> bijective).
  const int wgid = blockIdx.x;
  const int orig = (wgid & 7) * 64 + (wgid >> 3);
  const int bh = orig >> 4, qt = orig & 15;

  const unsigned short* qhb = qhi + (size_t)bh * S * HD;
  const unsigned short* qlb = qlo + (size_t)bh * S * HD;
  const unsigned short* khb = khi + (size_t)bh * S * HD;
  const unsigned short* klb = klo + (size_t)bh * S * HD;
  const unsigned short* vbase = vt + (size_t)bh * HD * S;
  const float* rbase = rs + (size_t)bh * S;
  const int qrow0 = qt * 128 + w * 32;

  // staging map (gemm-verified): call c stages rows c*32 + w*8 + (l>>3)
  const int srow8 = l >> 3;                 // 0..7
  const int sg = (l & 7) ^ srow8;           // pre-swizzled source granule

  s16x8 aqh[2][2], aql[2][2];
  #pragma unroll
  for (int mi = 0; mi < 2; ++mi)
    #pragma unroll
    for (int ks = 0; ks < 2; ++ks) {
      const size_t off = (size_t)(qrow0 + mi * 16 + lo) * HD + ks * 32 + hi * 8;
      aqh[mi][ks] = *(const s16x8*)(qhb + off);
      aql[mi][ks] = *(const s16x8*)(qlb + off);
    }

  float rsq[2][4];
  #pragma unroll
  for (int mi = 0; mi < 2; ++mi)
    #pragma unroll
    for (int r = 0; r < 4; ++r)
      rsq[mi][r] = rbase[qrow0 + mi * 16 + hi * 4 + r];

  f32x4 oacc[2][4];
  float den[2][4];
  #pragma unroll
  for (int mi = 0; mi < 2; ++mi)
    #pragma unroll
    for (int nd = 0; nd < 4; ++nd) {
      oacc[mi][nd] = (f32x4){0.f, 0.f, 0.f, 0.f};
      den[mi][nd] = 0.f;
    }

  for (int j0 = 0; j0 < S; j0 += 64) {
    __syncthreads();                         // prior iter's LDS reads done
    #pragma unroll
    for (int c = 0; c < 2; ++c) {
      const int row = c * 32 + w * 8 + srow8;
      const size_t kgo = (size_t)(j0 + row) * HD + sg * 8;
      const int dst = c * 2048 + w * 512;    // wave-uniform LDS base
      gload_lds16(khb + kgo, Kh + dst);
      gload_lds16(klb + kgo, Kl + dst);
      gload_lds16(vbase + (size_t)row * S + j0 + sg * 8, Vsm + dst);
    }
    // per-iter column scales, straight from global (L1/L2-resident)
    float rjv[4];
    #pragma unroll
    for (int nj = 0; nj < 4; ++nj) rjv[nj] = rbase[j0 + nj * 16 + lo];
    __syncthreads();                         // vmcnt(0) drain + barrier

    // QK^T (split 3-product) + scale/clip/exp + pack P (wave-local rows)
    #pragma unroll
    for (int mi = 0; mi < 2; ++mi) {
      #pragma unroll
      for (int nj = 0; nj < 4; ++nj) {
        f32x4 acc = (f32x4){0.f, 0.f, 0.f, 0.f};
        #pragma unroll
        for (int ks = 0; ks < 2; ++ks) {
          const int off = (nj * 16 + lo) * 64 + (((ks * 4 + hi) ^ (lo & 7)) << 3);
          s16x8 bkh = *(const s16x8*)&Kh[off];
          s16x8 bkl = *(const s16x8*)&Kl[off];
          acc = __builtin_amdgcn_mfma_f32_16x16x32_bf16(aqh[mi][ks], bkh, acc, 0, 0, 0);
          acc = __builtin_amdgcn_mfma_f32_16x16x32_bf16(aqh[mi][ks], bkl, acc, 0, 0, 0);
          acc = __builtin_amdgcn_mfma_f32_16x16x32_bf16(aql[mi][ks], bkh, acc, 0, 0, 0);
        }
        #pragma unroll
        for (int r = 0; r < 4; ++r) {
          float c = acc[r] * rsq[mi][r] * rjv[nj];   // rs==0 -> c==0 -> e==1
          c = fminf(1.f, fmaxf(-1.f, c));
          const float e = __expf(c);
          den[mi][r] += e;
          const int pr = w * 32 + mi * 16 + hi * 4 + r;
          Ps[pr * 64 + ((((nj * 2) + (lo >> 3)) ^ (pr & 7)) << 3) + (lo & 7)] = f2bf(e);
        }
      }
    }

    // PV: A = P (rows of this wave), B = V^T tile
    #pragma unroll
    for (int mi = 0; mi < 2; ++mi) {
      const int prow = w * 32 + mi * 16 + lo;
      s16x8 pa0 = *(const s16x8*)&Ps[prow * 64 + ((hi ^ (lo & 7)) << 3)];
      s16x8 pa1 = *(const s16x8*)&Ps[prow * 64 + (((4 + hi) ^ (lo & 7)) << 3)];
      #pragma unroll
      for (int nd = 0; nd < 4; ++nd) {
        const int vrow = nd * 16 + lo;
        s16x8 bv0 = *(const s16x8*)&Vsm[vrow * 64 + ((hi ^ (lo & 7)) << 3)];
        s16x8 bv1 = *(const s16x8*)&Vsm[vrow * 64 + (((4 + hi) ^ (lo & 7)) << 3)];
        oacc[mi][nd] = __builtin_amdgcn_mfma_f32_16x16x32_bf16(pa0, bv0, oacc[mi][nd], 0, 0, 0);
        oacc[mi][nd] = __builtin_amdgcn_mfma_f32_16x16x32_bf16(pa1, bv1, oacc[mi][nd], 0, 0, 0);
      }
    }
  }

  // reduce denominators across the 16 lanes sharing each row, then store
  #pragma unroll
  for (int mi = 0; mi < 2; ++mi)
    #pragma unroll
    for (int r = 0; r < 4; ++r) {
      float dsum = den[mi][r];
      dsum += __shfl_xor(dsum, 1, 64);
      dsum += __shfl_xor(dsum, 2, 64);
      dsum += __shfl_xor(dsum, 4, 64);
      dsum += __shfl_xor(dsum, 8, 64);
      den[mi][r] = 1.f / dsum;
    }
  #pragma unroll
  for (int mi = 0; mi < 2; ++mi)
    #pragma unroll
    for (int nd = 0; nd < 4; ++nd)
      #pragma unroll
      for (int r = 0; r < 4; ++r) {
        const size_t row = (size_t)bh * S + qrow0 + mi * 16 + hi * 4 + r;
        out[row * HD + nd * 16 + lo] = oacc[mi][nd][r] * den[mi][r];
      }
}

extern "C" void kernel_launch(void* const* d_in, const int* in_sizes, int n_in,
                              void* d_out, int out_size, void* d_ws, size_t ws_size,
                              hipStream_t stream) {
  const float* query = (const float*)d_in[0];
  const float* W     = (const float*)d_in[1];
  const float* bias  = (const float*)d_in[2];
  float* out = (float*)d_out;
  char* ws = (char*)d_ws;

  float*          qkv = (float*)ws;                          // [0, 50331648)
  // fp16 split planes live only between split_k and gemm_mfma:
  unsigned short* A1 = (unsigned short*)(ws + 50331648);     // 8388608
  unsigned short* A2 = (unsigned short*)(ws + 58720256);     // 8388608
  unsigned short* W1 = (unsigned short*)(ws + 67108864);     // 6291456
  unsigned short* W2 = (unsigned short*)(ws + 73400320);     // 6291456 -> 79691776
  // stats outputs reuse the (dead) split region:
  unsigned short* qhi = (unsigned short*)(ws + 50331648);
  unsigned short* qlo = (unsigned short*)(ws + 58720256);
  unsigned short* khi = (unsigned short*)(ws + 67108864);
  unsigned short* klo = (unsigned short*)(ws + 75497472);
  unsigned short* vt  = (unsigned short*)(ws + 83886080);
  float*          rsb = (float*)(ws + 92274688);

  split_k  <<<dim3(7168), 256, 0, stream>>>(query, W, A1, A2, W1, W2);
  gemm_mfma<<<dim3(24, 32), 256, 0, stream>>>(A1, A2, W1, W2, bias, qkv);
  stats_k  <<<dim3(32, 32), 256, 0, stream>>>(qkv, qhi, qlo, khi, klo, vt, rsb);
  attn_k   <<<dim3(512), 256, 0, stream>>>(qhi, qlo, khi, klo, vt, rsb, out);
}

// Round 6
// 177.722 us; speedup vs baseline: 2.2970x; 1.0827x over previous
//
#include <hip/hip_runtime.h>

#define S 2048
#define D 1024
#define NH 16
#define HD 64
#define N3 3072         // 3 * D
#define M 4096          // T * B

typedef short s16x8 __attribute__((ext_vector_type(8)));
typedef _Float16 f16x8 __attribute__((ext_vector_type(8)));
typedef float f32x4 __attribute__((ext_vector_type(4)));
typedef unsigned int u32;

__device__ __forceinline__ unsigned short f2bf(float f) {
  unsigned u = __builtin_bit_cast(unsigned, f);
  u += 0x7fffu + ((u >> 16) & 1u);
  return (unsigned short)(u >> 16);
}
__device__ __forceinline__ float bf2f(unsigned short h) {
  return __builtin_bit_cast(float, (unsigned)h << 16);
}

__device__ __forceinline__ float wsum(float v) {
  #pragma unroll
  for (int m = 1; m < 64; m <<= 1) v += __shfl_xor(v, m, 64);
  return v;
}

__device__ __forceinline__ void gload_lds16(const unsigned short* g, unsigned short* l) {
  __builtin_amdgcn_global_load_lds(
      (const __attribute__((address_space(1))) u32*)g,
      (__attribute__((address_space(3))) u32*)l, 16, 0, 0);
}

// ---------------------------------------------------------------------------
// Kernel 0: split f32 -> 2x fp16 limbs (verified r4).
// ---------------------------------------------------------------------------
__global__ __launch_bounds__(256) void split_k(const float* __restrict__ q,
                                               const float* __restrict__ w,
                                               unsigned short* __restrict__ A1,
                                               unsigned short* __restrict__ A2,
                                               unsigned short* __restrict__ W1,
                                               unsigned short* __restrict__ W2) {
  const size_t gid = (size_t)blockIdx.x * 256 + threadIdx.x;   // quad index
  const size_t NA = (size_t)M * D / 4;                          // 1048576
  float4 x;
  unsigned short* p1; unsigned short* p2; size_t qi; float scale;
  if (gid < NA) {
    qi = gid;  x = ((const float4*)q)[qi];
    p1 = A1; p2 = A2; scale = 64.f;
  } else {
    qi = gid - NA;  x = ((const float4*)w)[qi];
    p1 = W1; p2 = W2; scale = 1024.f;
  }
  float e[4] = {x.x * scale, x.y * scale, x.z * scale, x.w * scale};
  unsigned short h1[4], h2[4];
  #pragma unroll
  for (int i = 0; i < 4; ++i) {
    _Float16 a = (_Float16)e[i];
    float r = e[i] - (float)a;
    _Float16 b = (_Float16)r;
    h1[i] = __builtin_bit_cast(unsigned short, a);
    h2[i] = __builtin_bit_cast(unsigned short, b);
  }
  *(ushort4*)&p1[qi * 4] = make_ushort4(h1[0], h1[1], h1[2], h1[3]);
  *(ushort4*)&p2[qi * 4] = make_ushort4(h2[0], h2[1], h2[2], h2[3]);
}

// ---------------------------------------------------------------------------
// Kernel 1: emulated-f32 GEMM on fp16 MFMA (verified r4, unchanged).
// ---------------------------------------------------------------------------
__global__ __launch_bounds__(256) void gemm_mfma(const unsigned short* __restrict__ A1,
                                                 const unsigned short* __restrict__ A2,
                                                 const unsigned short* __restrict__ W1,
                                                 const unsigned short* __restrict__ W2,
                                                 const float* __restrict__ bias,
                                                 float* __restrict__ C) {
  __shared__ unsigned short As[128 * 64];
  __shared__ unsigned short Bs[128 * 64];
  const int tid = threadIdx.x;
  const int w = tid >> 6, l = tid & 63;
  const int lo = l & 15, hi = l >> 4;
  const int n0 = blockIdx.x * 128, m0 = blockIdx.y * 128;
  const int wr = w >> 1, wc = w & 1;          // wave tile 64x64

  const int nseg = (n0 >= 2048) ? 1 : 3;

  const int srow = (tid >> 3) & 31;
  const int skc = tid & 7;

  f32x4 acc[4][4];
  #pragma unroll
  for (int mi = 0; mi < 4; ++mi)
    #pragma unroll
    for (int nj = 0; nj < 4; ++nj) acc[mi][nj] = (f32x4){0.f, 0.f, 0.f, 0.f};

  for (int s = 0; s < 3; ++s) {
    if (s >= nseg) break;
    const unsigned short* Ab;
    const unsigned short* Bb;
    switch (s) {                               // uniform scalar branch
      case 0: Ab = A1; Bb = W1; break;
      case 1: Ab = A2; Bb = W1; break;
      default: Ab = A1; Bb = W2; break;
    }
    Ab += (size_t)m0 * D;
    Bb += (size_t)n0 * D;

    for (int k0 = 0; k0 < D; k0 += 64) {
      __syncthreads();                         // prior iter's LDS reads done
      #pragma unroll
      for (int c = 0; c < 4; ++c) {
        const int row = c * 32 + srow;
        const int koct = skc ^ (row & 7);      // pre-swizzled source
        gload_lds16(Ab + (size_t)row * D + k0 + koct * 8,
                    As + c * 2048 + w * 512);
        gload_lds16(Bb + (size_t)row * D + k0 + koct * 8,
                    Bs + c * 2048 + w * 512);
      }
      __syncthreads();

      f16x8 af[4][2], bf[4][2];
      #pragma unroll
      for (int mi = 0; mi < 4; ++mi)
        #pragma unroll
        for (int ks = 0; ks < 2; ++ks) {
          const int row = wr * 64 + mi * 16 + lo;
          const int koct = (ks * 4 + hi) ^ (lo & 7);
          af[mi][ks] = *(const f16x8*)&As[row * 64 + koct * 8];
        }
      #pragma unroll
      for (int nj = 0; nj < 4; ++nj)
        #pragma unroll
        for (int ks = 0; ks < 2; ++ks) {
          const int row = wc * 64 + nj * 16 + lo;
          const int koct = (ks * 4 + hi) ^ (lo & 7);
          bf[nj][ks] = *(const f16x8*)&Bs[row * 64 + koct * 8];
        }
      #pragma unroll
      for (int mi = 0; mi < 4; ++mi)
        #pragma unroll
        for (int nj = 0; nj < 4; ++nj)
          #pragma unroll
          for (int ks = 0; ks < 2; ++ks)
            acc[mi][nj] = __builtin_amdgcn_mfma_f32_16x16x32_f16(
                af[mi][ks], bf[nj][ks], acc[mi][nj], 0, 0, 0);
    }
  }

  #pragma unroll
  for (int mi = 0; mi < 4; ++mi)
    #pragma unroll
    for (int nj = 0; nj < 4; ++nj) {
      const int n = n0 + wc * 64 + nj * 16 + lo;
      const float bj = bias[n];
      #pragma unroll
      for (int r = 0; r < 4; ++r) {
        const int m = m0 + wr * 64 + mi * 16 + hi * 4 + r;
        C[(size_t)m * N3 + n] = acc[mi][nj][r] * (1.f / 65536.f) + bj;
      }
    }
}

// ---------------------------------------------------------------------------
// Kernel 2: per-row stats + layout conversion.
// r6: the rsqrt(d) scale is FOLDED into the limbs: q^ = qc*rs, k^ = kc*rs
// (scale-invariant: sign/flip behavior identical to the verified r2-r5
// config; rs=0 rows give q^=0 -> c=0 -> e=1 -> uniform, same semantics).
// attn then computes c = clip(q^.k^) with zero per-element scale VALU.
// ---------------------------------------------------------------------------
__global__ __launch_bounds__(256) void stats_k(const float* __restrict__ qkv,
                                               unsigned short* __restrict__ qhi,
                                               unsigned short* __restrict__ qlo,
                                               unsigned short* __restrict__ khi,
                                               unsigned short* __restrict__ klo,
                                               unsigned short* __restrict__ vt) {
  __shared__ unsigned short VsT[64][65];
  const int tt = blockIdx.x, bh = blockIdx.y;
  const int b = bh >> 4, h = bh & 15;
  const int w = threadIdx.x >> 6, l = threadIdx.x & 63;

  for (int rr = 0; rr < 16; ++rr) {
    const int t = tt * 64 + w * 16 + rr;
    const size_t base = (size_t)(t * 2 + b) * N3 + h * HD;
    const float q = qkv[base + l];
    const float k = qkv[base + D + l];
    const float v = qkv[base + 2 * D + l];
    const float qm = wsum(q) * (1.f / 64.f);
    const float km = wsum(k) * (1.f / 64.f);
    const float qcv = q - qm, kcv = k - km;
    const float d = wsum(qcv * kcv);
    float rv = 0.f;
    if (d > 0.f) {
      rv = rsqrtf(d);
      rv = rv * (1.5f - 0.5f * d * rv * rv);   // one NR step
    }
    const float qn = qcv * rv, kn = kcv * rv;  // normalized rows
    const size_t ro = ((size_t)bh * S + t) * HD + l;
    const unsigned short qh = f2bf(qn);
    const unsigned short kh = f2bf(kn);
    qhi[ro] = qh;  qlo[ro] = f2bf(qn - bf2f(qh));
    khi[ro] = kh;  klo[ro] = f2bf(kn - bf2f(kh));
    VsT[l][w * 16 + rr] = f2bf(v);
  }
  __syncthreads();
  const int dd = threadIdx.x >> 2, seg = threadIdx.x & 3;
  unsigned pk[8];
  #pragma unroll
  for (int e = 0; e < 8; ++e) {
    unsigned l2 = VsT[dd][seg * 16 + 2 * e];
    unsigned h2 = VsT[dd][seg * 16 + 2 * e + 1];
    pk[e] = l2 | (h2 << 16);
  }
  unsigned short* dst = vt + ((size_t)bh * HD + dd) * S + tt * 64 + seg * 16;
  *(uint4*)dst       = make_uint4(pk[0], pk[1], pk[2], pk[3]);
  *(uint4*)(dst + 8) = make_uint4(pk[4], pk[5], pk[6], pk[7]);
}

// ---------------------------------------------------------------------------
// Kernel 3: fused correlation-softmax-PV.
// r6: 8 waves (512 thr), 16 q-rows/wave, QB=128, grid 512 -> 16 waves/CU
// (was 8); softmax has zero scale-muls (normalization folded upstream).
// LDS layouts and staging identical to the r5 zero-conflict patterns.
// ---------------------------------------------------------------------------
__global__ __launch_bounds__(512) void attn_k(const unsigned short* __restrict__ qhi,
                                              const unsigned short* __restrict__ qlo,
                                              const unsigned short* __restrict__ khi,
                                              const unsigned short* __restrict__ klo,
                                              const unsigned short* __restrict__ vt,
                                              float* __restrict__ out) {
  __shared__ unsigned short Kh[64 * 64];   // [row j][64 k], XOR-granule
  __shared__ unsigned short Kl[64 * 64];
  __shared__ unsigned short Vsm[64 * 64];  // [row d][64 j], XOR-granule
  __shared__ unsigned short Ps[128 * 64];  // [row q][64 j], XOR-granule

  const int tid = threadIdx.x;
  const int w = tid >> 6, l = tid & 63;
  const int lo = l & 15, hi = l >> 4;

  // T1: XCD-aware swizzle (512 = 8 XCD x 64, exact -> bijective).
  const int wgid = blockIdx.x;
  const int orig = (wgid & 7) * 64 + (wgid >> 3);
  const int bh = orig >> 4, qt = orig & 15;

  const unsigned short* qhb = qhi + (size_t)bh * S * HD;
  const unsigned short* qlb = qlo + (size_t)bh * S * HD;
  const unsigned short* khb = khi + (size_t)bh * S * HD;
  const unsigned short* klb = klo + (size_t)bh * S * HD;
  const unsigned short* vbase = vt + (size_t)bh * HD * S;
  const int qrow0 = qt * 128 + w * 16;     // wave owns 16 q-rows

  // staging map: thread stages one 16B chunk per plane; linear LDS dest
  const int srow = tid >> 3;               // 0..63
  const int sg = (tid & 7) ^ (srow & 7);   // pre-swizzled source granule

  // Q fragments (this wave's 16 rows): row=lo, k=ks*32+hi*8
  s16x8 aqh[2], aql[2];
  #pragma unroll
  for (int ks = 0; ks < 2; ++ks) {
    const size_t off = (size_t)(qrow0 + lo) * HD + ks * 32 + hi * 8;
    aqh[ks] = *(const s16x8*)(qhb + off);
    aql[ks] = *(const s16x8*)(qlb + off);
  }

  f32x4 oacc[4];
  float den[4];
  #pragma unroll
  for (int nd = 0; nd < 4; ++nd) { oacc[nd] = (f32x4){0.f, 0.f, 0.f, 0.f}; den[nd] = 0.f; }

  for (int j0 = 0; j0 < S; j0 += 64) {
    __syncthreads();                       // prior iter's LDS reads done
    {
      const size_t kgo = (size_t)(j0 + srow) * HD + sg * 8;
      gload_lds16(khb + kgo, Kh + w * 512);
      gload_lds16(klb + kgo, Kl + w * 512);
      gload_lds16(vbase + (size_t)srow * S + j0 + sg * 8, Vsm + w * 512);
    }
    __syncthreads();                       // vmcnt(0) drain + barrier

    // QK^T (split 3-product) + clip/exp + pack P (wave-local rows)
    #pragma unroll
    for (int nj = 0; nj < 4; ++nj) {
      f32x4 acc = (f32x4){0.f, 0.f, 0.f, 0.f};
      #pragma unroll
      for (int ks = 0; ks < 2; ++ks) {
        const int off = (nj * 16 + lo) * 64 + (((ks * 4 + hi) ^ (lo & 7)) << 3);
        s16x8 bkh = *(const s16x8*)&Kh[off];
        s16x8 bkl = *(const s16x8*)&Kl[off];
        acc = __builtin_amdgcn_mfma_f32_16x16x32_bf16(aqh[ks], bkh, acc, 0, 0, 0);
        acc = __builtin_amdgcn_mfma_f32_16x16x32_bf16(aqh[ks], bkl, acc, 0, 0, 0);
        acc = __builtin_amdgcn_mfma_f32_16x16x32_bf16(aql[ks], bkh, acc, 0, 0, 0);
      }
      #pragma unroll
      for (int r = 0; r < 4; ++r) {
        float c = fminf(1.f, fmaxf(-1.f, acc[r]));  // q^=0 row -> c=0 -> e=1
        const float e = __expf(c);
        den[r] += e;
        const int pr = w * 16 + hi * 4 + r;
        Ps[pr * 64 + ((((nj * 2) + (lo >> 3)) ^ (pr & 7)) << 3) + (lo & 7)] = f2bf(e);
      }
    }

    // PV: A = P (this wave's 16 rows), B = V^T tile
    {
      const int prow = w * 16 + lo;
      s16x8 pa0 = *(const s16x8*)&Ps[prow * 64 + ((hi ^ (lo & 7)) << 3)];
      s16x8 pa1 = *(const s16x8*)&Ps[prow * 64 + (((4 + hi) ^ (lo & 7)) << 3)];
      #pragma unroll
      for (int nd = 0; nd < 4; ++nd) {
        const int vrow = nd * 16 + lo;
        s16x8 bv0 = *(const s16x8*)&Vsm[vrow * 64 + ((hi ^ (lo & 7)) << 3)];
        s16x8 bv1 = *(const s16x8*)&Vsm[vrow * 64 + (((4 + hi) ^ (lo & 7)) << 3)];
        oacc[nd] = __builtin_amdgcn_mfma_f32_16x16x32_bf16(pa0, bv0, oacc[nd], 0, 0, 0);
        oacc[nd] = __builtin_amdgcn_mfma_f32_16x16x32_bf16(pa1, bv1, oacc[nd], 0, 0, 0);
      }
    }
  }

  // reduce denominators across the 16 lanes sharing each row, then store
  #pragma unroll
  for (int r = 0; r < 4; ++r) {
    float dsum = den[r];
    dsum += __shfl_xor(dsum, 1, 64);
    dsum += __shfl_xor(dsum, 2, 64);
    dsum += __shfl_xor(dsum, 4, 64);
    dsum += __shfl_xor(dsum, 8, 64);
    den[r] = 1.f / dsum;
  }
  #pragma unroll
  for (int nd = 0; nd < 4; ++nd)
    #pragma unroll
    for (int r = 0; r < 4; ++r) {
      const size_t row = (size_t)bh * S + qrow0 + hi * 4 + r;
      out[row * HD + nd * 16 + lo] = oacc[nd][r] * den[r];
    }
}

extern "C" void kernel_launch(void* const* d_in, const int* in_sizes, int n_in,
                              void* d_out, int out_size, void* d_ws, size_t ws_size,
                              hipStream_t stream) {
  const float* query = (const float*)d_in[0];
  const float* W     = (const float*)d_in[1];
  const float* bias  = (const float*)d_in[2];
  float* out = (float*)d_out;
  char* ws = (char*)d_ws;

  float*          qkv = (float*)ws;                          // [0, 50331648)
  // fp16 split planes live only between split_k and gemm_mfma:
  unsigned short* A1 = (unsigned short*)(ws + 50331648);     // 8388608
  unsigned short* A2 = (unsigned short*)(ws + 58720256);     // 8388608
  unsigned short* W1 = (unsigned short*)(ws + 67108864);     // 6291456
  unsigned short* W2 = (unsigned short*)(ws + 73400320);     // 6291456 -> 79691776
  // stats outputs reuse the (dead) split region:
  unsigned short* qhi = (unsigned short*)(ws + 50331648);
  unsigned short* qlo = (unsigned short*)(ws + 58720256);
  unsigned short* khi = (unsigned short*)(ws + 67108864);
  unsigned short* klo = (unsigned short*)(ws + 75497472);
  unsigned short* vt  = (unsigned short*)(ws + 83886080);

  split_k  <<<dim3(7168), 256, 0, stream>>>(query, W, A1, A2, W1, W2);
  gemm_mfma<<<dim3(24, 32), 256, 0, stream>>>(A1, A2, W1, W2, bias, qkv);
  stats_k  <<<dim3(32, 32), 256, 0, stream>>>(qkv, qhi, qlo, khi, klo, vt);
  attn_k   <<<dim3(512), 512, 0, stream>>>(qhi, qlo, khi, klo, vt, out);
}

// Round 7
// 176.598 us; speedup vs baseline: 2.3116x; 1.0064x over previous
//
#include <hip/hip_runtime.h>

#define S 2048
#define D 1024
#define NH 16
#define HD 64
#define N3 3072         // 3 * D
#define M 4096          // T * B

typedef short s16x8 __attribute__((ext_vector_type(8)));
typedef _Float16 f16x8 __attribute__((ext_vector_type(8)));
typedef _Float16 f16x2 __attribute__((ext_vector_type(2)));
typedef float f32x4 __attribute__((ext_vector_type(4)));
typedef unsigned int u32;
typedef u32 u32x4 __attribute__((ext_vector_type(4)));

__device__ __forceinline__ unsigned short f2bf(float f) {
  unsigned u = __builtin_bit_cast(unsigned, f);
  u += 0x7fffu + ((u >> 16) & 1u);
  return (unsigned short)(u >> 16);
}
__device__ __forceinline__ float bf2f(unsigned short h) {
  return __builtin_bit_cast(float, (unsigned)h << 16);
}
__device__ __forceinline__ unsigned short f2h(float f) {
  _Float16 h = (_Float16)f;
  return __builtin_bit_cast(unsigned short, h);
}

__device__ __forceinline__ float wsum(float v) {
  #pragma unroll
  for (int m = 1; m < 64; m <<= 1) v += __shfl_xor(v, m, 64);
  return v;
}

__device__ __forceinline__ void gload_lds16(const unsigned short* g, unsigned short* l) {
  __builtin_amdgcn_global_load_lds(
      (const __attribute__((address_space(1))) u32*)g,
      (__attribute__((address_space(3))) u32*)l, 16, 0, 0);
}

// ---------------------------------------------------------------------------
// Kernel 0: split f32 -> 2x fp16 limbs (verified r4).
// ---------------------------------------------------------------------------
__global__ __launch_bounds__(256) void split_k(const float* __restrict__ q,
                                               const float* __restrict__ w,
                                               unsigned short* __restrict__ A1,
                                               unsigned short* __restrict__ A2,
                                               unsigned short* __restrict__ W1,
                                               unsigned short* __restrict__ W2) {
  const size_t gid = (size_t)blockIdx.x * 256 + threadIdx.x;   // quad index
  const size_t NA = (size_t)M * D / 4;                          // 1048576
  float4 x;
  unsigned short* p1; unsigned short* p2; size_t qi; float scale;
  if (gid < NA) {
    qi = gid;  x = ((const float4*)q)[qi];
    p1 = A1; p2 = A2; scale = 64.f;
  } else {
    qi = gid - NA;  x = ((const float4*)w)[qi];
    p1 = W1; p2 = W2; scale = 1024.f;
  }
  float e[4] = {x.x * scale, x.y * scale, x.z * scale, x.w * scale};
  unsigned short h1[4], h2[4];
  #pragma unroll
  for (int i = 0; i < 4; ++i) {
    _Float16 a = (_Float16)e[i];
    float r = e[i] - (float)a;
    _Float16 b = (_Float16)r;
    h1[i] = __builtin_bit_cast(unsigned short, a);
    h2[i] = __builtin_bit_cast(unsigned short, b);
  }
  *(ushort4*)&p1[qi * 4] = make_ushort4(h1[0], h1[1], h1[2], h1[3]);
  *(ushort4*)&p2[qi * 4] = make_ushort4(h2[0], h2[1], h2[2], h2[3]);
}

// ---------------------------------------------------------------------------
// Kernel 1: emulated-f32 GEMM on fp16 MFMA (verified r4, unchanged).
// ---------------------------------------------------------------------------
__global__ __launch_bounds__(256) void gemm_mfma(const unsigned short* __restrict__ A1,
                                                 const unsigned short* __restrict__ A2,
                                                 const unsigned short* __restrict__ W1,
                                                 const unsigned short* __restrict__ W2,
                                                 const float* __restrict__ bias,
                                                 float* __restrict__ C) {
  __shared__ unsigned short As[128 * 64];
  __shared__ unsigned short Bs[128 * 64];
  const int tid = threadIdx.x;
  const int w = tid >> 6, l = tid & 63;
  const int lo = l & 15, hi = l >> 4;
  const int n0 = blockIdx.x * 128, m0 = blockIdx.y * 128;
  const int wr = w >> 1, wc = w & 1;          // wave tile 64x64

  const int nseg = (n0 >= 2048) ? 1 : 3;

  const int srow = (tid >> 3) & 31;
  const int skc = tid & 7;

  f32x4 acc[4][4];
  #pragma unroll
  for (int mi = 0; mi < 4; ++mi)
    #pragma unroll
    for (int nj = 0; nj < 4; ++nj) acc[mi][nj] = (f32x4){0.f, 0.f, 0.f, 0.f};

  for (int s = 0; s < 3; ++s) {
    if (s >= nseg) break;
    const unsigned short* Ab;
    const unsigned short* Bb;
    switch (s) {                               // uniform scalar branch
      case 0: Ab = A1; Bb = W1; break;
      case 1: Ab = A2; Bb = W1; break;
      default: Ab = A1; Bb = W2; break;
    }
    Ab += (size_t)m0 * D;
    Bb += (size_t)n0 * D;

    for (int k0 = 0; k0 < D; k0 += 64) {
      __syncthreads();                         // prior iter's LDS reads done
      #pragma unroll
      for (int c = 0; c < 4; ++c) {
        const int row = c * 32 + srow;
        const int koct = skc ^ (row & 7);      // pre-swizzled source
        gload_lds16(Ab + (size_t)row * D + k0 + koct * 8,
                    As + c * 2048 + w * 512);
        gload_lds16(Bb + (size_t)row * D + k0 + koct * 8,
                    Bs + c * 2048 + w * 512);
      }
      __syncthreads();

      f16x8 af[4][2], bf[4][2];
      #pragma unroll
      for (int mi = 0; mi < 4; ++mi)
        #pragma unroll
        for (int ks = 0; ks < 2; ++ks) {
          const int row = wr * 64 + mi * 16 + lo;
          const int koct = (ks * 4 + hi) ^ (lo & 7);
          af[mi][ks] = *(const f16x8*)&As[row * 64 + koct * 8];
        }
      #pragma unroll
      for (int nj = 0; nj < 4; ++nj)
        #pragma unroll
        for (int ks = 0; ks < 2; ++ks) {
          const int row = wc * 64 + nj * 16 + lo;
          const int koct = (ks * 4 + hi) ^ (lo & 7);
          bf[nj][ks] = *(const f16x8*)&Bs[row * 64 + koct * 8];
        }
      #pragma unroll
      for (int mi = 0; mi < 4; ++mi)
        #pragma unroll
        for (int nj = 0; nj < 4; ++nj)
          #pragma unroll
          for (int ks = 0; ks < 2; ++ks)
            acc[mi][nj] = __builtin_amdgcn_mfma_f32_16x16x32_f16(
                af[mi][ks], bf[nj][ks], acc[mi][nj], 0, 0, 0);
    }
  }

  #pragma unroll
  for (int mi = 0; mi < 4; ++mi)
    #pragma unroll
    for (int nj = 0; nj < 4; ++nj) {
      const int n = n0 + wc * 64 + nj * 16 + lo;
      const float bj = bias[n];
      #pragma unroll
      for (int r = 0; r < 4; ++r) {
        const int m = m0 + wr * 64 + mi * 16 + hi * 4 + r;
        C[(size_t)m * N3 + n] = acc[mi][nj][r] * (1.f / 65536.f) + bj;
      }
    }
}

// ---------------------------------------------------------------------------
// Kernel 2: per-row stats + layout conversion.
// q^ = qc*rs, k^ = kc*rs folded limbs (bf16, r6-verified);
// r7: V stored as fp16 (8x less quantization than bf16; |v|<~6 fp16-safe).
// ---------------------------------------------------------------------------
__global__ __launch_bounds__(256) void stats_k(const float* __restrict__ qkv,
                                               unsigned short* __restrict__ qhi,
                                               unsigned short* __restrict__ qlo,
                                               unsigned short* __restrict__ khi,
                                               unsigned short* __restrict__ klo,
                                               unsigned short* __restrict__ vt) {
  __shared__ unsigned short VsT[64][65];
  const int tt = blockIdx.x, bh = blockIdx.y;
  const int b = bh >> 4, h = bh & 15;
  const int w = threadIdx.x >> 6, l = threadIdx.x & 63;

  for (int rr = 0; rr < 16; ++rr) {
    const int t = tt * 64 + w * 16 + rr;
    const size_t base = (size_t)(t * 2 + b) * N3 + h * HD;
    const float q = qkv[base + l];
    const float k = qkv[base + D + l];
    const float v = qkv[base + 2 * D + l];
    const float qm = wsum(q) * (1.f / 64.f);
    const float km = wsum(k) * (1.f / 64.f);
    const float qcv = q - qm, kcv = k - km;
    const float d = wsum(qcv * kcv);
    float rv = 0.f;
    if (d > 0.f) {
      rv = rsqrtf(d);
      rv = rv * (1.5f - 0.5f * d * rv * rv);   // one NR step
    }
    const float qn = qcv * rv, kn = kcv * rv;  // normalized rows
    const size_t ro = ((size_t)bh * S + t) * HD + l;
    const unsigned short qh = f2bf(qn);
    const unsigned short kh = f2bf(kn);
    qhi[ro] = qh;  qlo[ro] = f2bf(qn - bf2f(qh));
    khi[ro] = kh;  klo[ro] = f2bf(kn - bf2f(kh));
    VsT[l][w * 16 + rr] = f2h(v);              // fp16 V
  }
  __syncthreads();
  const int dd = threadIdx.x >> 2, seg = threadIdx.x & 3;
  unsigned pk[8];
  #pragma unroll
  for (int e = 0; e < 8; ++e) {
    unsigned l2 = VsT[dd][seg * 16 + 2 * e];
    unsigned h2 = VsT[dd][seg * 16 + 2 * e + 1];
    pk[e] = l2 | (h2 << 16);
  }
  unsigned short* dst = vt + ((size_t)bh * HD + dd) * S + tt * 64 + seg * 16;
  *(uint4*)dst       = make_uint4(pk[0], pk[1], pk[2], pk[3]);
  *(uint4*)(dst + 8) = make_uint4(pk[4], pk[5], pk[6], pk[7]);
}

// ---------------------------------------------------------------------------
// Kernel 3: fused correlation-softmax-PV, SWAPPED QK^T.
// mfma(K,Q) -> lane(lo,hi) holds S[q=lo][k=nj*16+hi*4+r]: softmax is fully
// lane-local; P assembled in-register (cvt_pkrtz fp16 + 16 shfl among the
// 4 lanes sharing lo) -> no P LDS roundtrip, no Ps buffer (LDS 24.5KB).
// K/V/Q fragment reads identical to the r6 zero-conflict patterns
// (operand-swap symmetry). PV in fp16 (P rtz, V rne).
// ---------------------------------------------------------------------------
__global__ __launch_bounds__(512, 4) void attn_k(const unsigned short* __restrict__ qhi,
                                                 const unsigned short* __restrict__ qlo,
                                                 const unsigned short* __restrict__ khi,
                                                 const unsigned short* __restrict__ klo,
                                                 const unsigned short* __restrict__ vt,
                                                 float* __restrict__ out) {
  __shared__ unsigned short Kh[64 * 64];   // [row j][64 d], XOR-granule
  __shared__ unsigned short Kl[64 * 64];
  __shared__ unsigned short Vsm[64 * 64];  // [row d][64 j], XOR-granule

  const int tid = threadIdx.x;
  const int w = tid >> 6, l = tid & 63;
  const int lo = l & 15, hi = l >> 4;

  // T1: XCD-aware swizzle (512 = 8 XCD x 64, exact -> bijective).
  const int wgid = blockIdx.x;
  const int orig = (wgid & 7) * 64 + (wgid >> 3);
  const int bh = orig >> 4, qt = orig & 15;

  const unsigned short* qhb = qhi + (size_t)bh * S * HD;
  const unsigned short* qlb = qlo + (size_t)bh * S * HD;
  const unsigned short* khb = khi + (size_t)bh * S * HD;
  const unsigned short* klb = klo + (size_t)bh * S * HD;
  const unsigned short* vbase = vt + (size_t)bh * HD * S;
  const int qrow0 = qt * 128 + w * 16;     // wave owns 16 q-rows

  // staging map: thread stages one 16B chunk per plane; linear LDS dest
  const int srow = tid >> 3;               // 0..63
  const int sg = (tid & 7) ^ (srow & 7);   // pre-swizzled source granule

  // Q fragments (B-operand): lane holds q-row qrow0+lo, d-chunk ks*32+hi*8
  s16x8 aqh[2], aql[2];
  #pragma unroll
  for (int ks = 0; ks < 2; ++ks) {
    const size_t off = (size_t)(qrow0 + lo) * HD + ks * 32 + hi * 8;
    aqh[ks] = *(const s16x8*)(qhb + off);
    aql[ks] = *(const s16x8*)(qlb + off);
  }

  f32x4 oacc[4];
  float den = 0.f;
  #pragma unroll
  for (int nd = 0; nd < 4; ++nd) oacc[nd] = (f32x4){0.f, 0.f, 0.f, 0.f};

  const int sel = hi >> 1;                 // which nj-parity this lane needs
  const int srcA = lo + ((hi & 1) << 5);   // lane with hi' = 2*(hi&1)
  const int srcB = srcA + 16;              // hi' = 2*(hi&1)+1

  for (int j0 = 0; j0 < S; j0 += 64) {
    __syncthreads();                       // prior iter's LDS reads done
    {
      const size_t kgo = (size_t)(j0 + srow) * HD + sg * 8;
      gload_lds16(khb + kgo, Kh + w * 512);
      gload_lds16(klb + kgo, Kl + w * 512);
      gload_lds16(vbase + (size_t)srow * S + j0 + sg * 8, Vsm + w * 512);
    }
    __syncthreads();                       // vmcnt(0) drain + barrier

    // swapped QK^T: acc_s[nj] = S[q=lo][k=nj*16+hi*4+r], 3-product split
    u32 pk2[4][2];
    #pragma unroll
    for (int nj = 0; nj < 4; ++nj) {
      f32x4 acc = (f32x4){0.f, 0.f, 0.f, 0.f};
      #pragma unroll
      for (int ks = 0; ks < 2; ++ks) {
        const int off = (nj * 16 + lo) * 64 + (((ks * 4 + hi) ^ (lo & 7)) << 3);
        s16x8 akh = *(const s16x8*)&Kh[off];
        s16x8 akl = *(const s16x8*)&Kl[off];
        acc = __builtin_amdgcn_mfma_f32_16x16x32_bf16(akh, aqh[ks], acc, 0, 0, 0);
        acc = __builtin_amdgcn_mfma_f32_16x16x32_bf16(akl, aqh[ks], acc, 0, 0, 0);
        acc = __builtin_amdgcn_mfma_f32_16x16x32_bf16(akh, aql[ks], acc, 0, 0, 0);
      }
      float e[4];
      #pragma unroll
      for (int r = 0; r < 4; ++r) {
        float c = fminf(1.f, fmaxf(-1.f, acc[r]));  // q^=0 row -> c=0 -> e=1
        e[r] = __expf(c);
        den += e[r];
      }
      pk2[nj][0] = __builtin_bit_cast(u32, __builtin_amdgcn_cvt_pkrtz(e[0], e[1]));
      pk2[nj][1] = __builtin_bit_cast(u32, __builtin_amdgcn_cvt_pkrtz(e[2], e[3]));
    }

    // in-register P transpose: pa[ks] = P[q=lo][k=ks*32+hi*8 .. +7]
    f16x8 pa[2];
    #pragma unroll
    for (int ks = 0; ks < 2; ++ks) {
      u32 a0 = __shfl(pk2[2 * ks][0], srcA, 64);
      u32 b0 = __shfl(pk2[2 * ks + 1][0], srcA, 64);
      u32 a1 = __shfl(pk2[2 * ks][1], srcA, 64);
      u32 b1 = __shfl(pk2[2 * ks + 1][1], srcA, 64);
      u32 a2 = __shfl(pk2[2 * ks][0], srcB, 64);
      u32 b2 = __shfl(pk2[2 * ks + 1][0], srcB, 64);
      u32 a3 = __shfl(pk2[2 * ks][1], srcB, 64);
      u32 b3 = __shfl(pk2[2 * ks + 1][1], srcB, 64);
      u32x4 u;
      u[0] = sel ? b0 : a0;
      u[1] = sel ? b1 : a1;
      u[2] = sel ? b2 : a2;
      u[3] = sel ? b3 : a3;
      pa[ks] = __builtin_bit_cast(f16x8, u);
    }

    // PV: O[q][d] += P V, A=pa (rows q), B=V (k=j, cols d) from Vsm
    #pragma unroll
    for (int nd = 0; nd < 4; ++nd) {
      const int vrow = nd * 16 + lo;
      f16x8 bv0 = *(const f16x8*)&Vsm[vrow * 64 + ((hi ^ (lo & 7)) << 3)];
      f16x8 bv1 = *(const f16x8*)&Vsm[vrow * 64 + (((4 + hi) ^ (lo & 7)) << 3)];
      oacc[nd] = __builtin_amdgcn_mfma_f32_16x16x32_f16(pa[0], bv0, oacc[nd], 0, 0, 0);
      oacc[nd] = __builtin_amdgcn_mfma_f32_16x16x32_f16(pa[1], bv1, oacc[nd], 0, 0, 0);
    }
  }

  // den: reduce the 4 hi-partials of each q-row, redistribute, store
  float d1 = den + __shfl_xor(den, 16, 64);
  float dtot = d1 + __shfl_xor(d1, 32, 64);
  float inv = 1.f / dtot;                   // valid for q = lo
  float dr[4];
  #pragma unroll
  for (int r = 0; r < 4; ++r) dr[r] = __shfl(inv, hi * 4 + r, 64);

  #pragma unroll
  for (int nd = 0; nd < 4; ++nd)
    #pragma unroll
    for (int r = 0; r < 4; ++r) {
      const size_t row = (size_t)bh * S + qrow0 + hi * 4 + r;
      out[row * HD + nd * 16 + lo] = oacc[nd][r] * dr[r];
    }
}

extern "C" void kernel_launch(void* const* d_in, const int* in_sizes, int n_in,
                              void* d_out, int out_size, void* d_ws, size_t ws_size,
                              hipStream_t stream) {
  const float* query = (const float*)d_in[0];
  const float* W     = (const float*)d_in[1];
  const float* bias  = (const float*)d_in[2];
  float* out = (float*)d_out;
  char* ws = (char*)d_ws;

  float*          qkv = (float*)ws;                          // [0, 50331648)
  // fp16 split planes live only between split_k and gemm_mfma:
  unsigned short* A1 = (unsigned short*)(ws + 50331648);     // 8388608
  unsigned short* A2 = (unsigned short*)(ws + 58720256);     // 8388608
  unsigned short* W1 = (unsigned short*)(ws + 67108864);     // 6291456
  unsigned short* W2 = (unsigned short*)(ws + 73400320);     // 6291456 -> 79691776
  // stats outputs reuse the (dead) split region:
  unsigned short* qhi = (unsigned short*)(ws + 50331648);
  unsigned short* qlo = (unsigned short*)(ws + 58720256);
  unsigned short* khi = (unsigned short*)(ws + 67108864);
  unsigned short* klo = (unsigned short*)(ws + 75497472);
  unsigned short* vt  = (unsigned short*)(ws + 83886080);

  split_k  <<<dim3(7168), 256, 0, stream>>>(query, W, A1, A2, W1, W2);
  gemm_mfma<<<dim3(24, 32), 256, 0, stream>>>(A1, A2, W1, W2, bias, qkv);
  stats_k  <<<dim3(32, 32), 256, 0, stream>>>(qkv, qhi, qlo, khi, klo, vt);
  attn_k   <<<dim3(512), 512, 0, stream>>>(qhi, qlo, khi, klo, vt, out);
}